// Round 1
// baseline (439.335 us; speedup 1.0000x reference)
//
#include <hip/hip_runtime.h>
#include <hip/hip_bf16.h>
#include <math.h>

#define DIM 128
#define NH 8
#define DH 16
#define TILE 32
#define LN_EPS 1e-5f

__device__ __forceinline__ float prelu_f(float x, float al) {
    return x >= 0.f ? x : al * x;
}

// ------------------------------------------------------------------
// Query-side projection: Qq = q@Wq+bq, Kq = q@Wk+bk, Vq = q@Wv+bv.
// Stores Qq, Vq and attn_qq[n,h] = sum_d a[d]*prelu(Qq+Kq).
// Block 256 threads, 32-row tile, 4x4 micro-tile per thread.
// ------------------------------------------------------------------
__global__ __launch_bounds__(256) void proj_query_kernel(
    const float* __restrict__ query,
    const float* __restrict__ Wq, const float* __restrict__ bq,
    const float* __restrict__ Wk, const float* __restrict__ bk,
    const float* __restrict__ Wv, const float* __restrict__ bv,
    const float* __restrict__ avec, const float* __restrict__ alpha_p,
    float* __restrict__ Qq, float* __restrict__ Vq,
    float* __restrict__ attnqq, int N)
{
    __shared__ __attribute__((aligned(16))) float xs[TILE][DIM];
    const int t = threadIdx.x;
    const int row0 = blockIdx.x * TILE;
    // stage 32 rows of query
    #pragma unroll
    for (int i = 0; i < (TILE * DIM) / 256; ++i) {
        int idx = t + i * 256;
        int r = idx >> 7, c = idx & 127;
        int gr = row0 + r;
        xs[r][c] = (gr < N) ? query[(size_t)gr * DIM + c] : 0.f;
    }
    __syncthreads();

    const int ty = t >> 5;   // 0..7  (4 rows each)
    const int tx = t & 31;   // 0..31 (4 cols each)
    const int c0 = tx * 4;

    float accQ[4][4] = {{0}}, accK[4][4] = {{0}}, accV[4][4] = {{0}};

    for (int k4 = 0; k4 < DIM; k4 += 4) {
        float xv[4][4];
        #pragma unroll
        for (int j = 0; j < 4; ++j)
            *(float4*)&xv[j][0] = *(const float4*)&xs[ty * 4 + j][k4];
        #pragma unroll
        for (int kk = 0; kk < 4; ++kk) {
            const float4 wq = *(const float4*)&Wq[(k4 + kk) * DIM + c0];
            const float4 wk = *(const float4*)&Wk[(k4 + kk) * DIM + c0];
            const float4 wv = *(const float4*)&Wv[(k4 + kk) * DIM + c0];
            #pragma unroll
            for (int j = 0; j < 4; ++j) {
                const float x = xv[j][kk];
                accQ[j][0] = fmaf(x, wq.x, accQ[j][0]);
                accQ[j][1] = fmaf(x, wq.y, accQ[j][1]);
                accQ[j][2] = fmaf(x, wq.z, accQ[j][2]);
                accQ[j][3] = fmaf(x, wq.w, accQ[j][3]);
                accK[j][0] = fmaf(x, wk.x, accK[j][0]);
                accK[j][1] = fmaf(x, wk.y, accK[j][1]);
                accK[j][2] = fmaf(x, wk.z, accK[j][2]);
                accK[j][3] = fmaf(x, wk.w, accK[j][3]);
                accV[j][0] = fmaf(x, wv.x, accV[j][0]);
                accV[j][1] = fmaf(x, wv.y, accV[j][1]);
                accV[j][2] = fmaf(x, wv.z, accV[j][2]);
                accV[j][3] = fmaf(x, wv.w, accV[j][3]);
            }
        }
    }

    const float al = alpha_p[0];
    float bq4[4], bk4[4], bv4[4], a4[4];
    *(float4*)bq4 = *(const float4*)&bq[c0];
    *(float4*)bk4 = *(const float4*)&bk[c0];
    *(float4*)bv4 = *(const float4*)&bv[c0];
    *(float4*)a4  = *(const float4*)&avec[c0];

    #pragma unroll
    for (int j = 0; j < 4; ++j) {
        const int gr = row0 + ty * 4 + j;
        const bool ok = gr < N;
        float q[4], kq[4], v[4];
        #pragma unroll
        for (int i = 0; i < 4; ++i) {
            q[i]  = accQ[j][i] + bq4[i];
            kq[i] = accK[j][i] + bk4[i];
            v[i]  = accV[j][i] + bv4[i];
        }
        if (ok) {
            *(float4*)&Qq[(size_t)gr * DIM + c0] = make_float4(q[0], q[1], q[2], q[3]);
            *(float4*)&Vq[(size_t)gr * DIM + c0] = make_float4(v[0], v[1], v[2], v[3]);
        }
        float part = 0.f;
        #pragma unroll
        for (int i = 0; i < 4; ++i)
            part += a4[i] * prelu_f(q[i] + kq[i], al);
        // reduce across the 4 lanes (tx%4 group) that share one head
        part += __shfl_xor(part, 1, 4);
        part += __shfl_xor(part, 2, 4);
        if (ok && (tx & 3) == 0)
            attnqq[(size_t)gr * NH + (tx >> 2)] = part;
    }
}

// ------------------------------------------------------------------
// Key/value-side projection: Kk = key@Wk+bk, Vv = value@Wv+bv.
// ------------------------------------------------------------------
__global__ __launch_bounds__(256) void proj_kv_kernel(
    const float* __restrict__ key, const float* __restrict__ value,
    const float* __restrict__ Wk, const float* __restrict__ bk,
    const float* __restrict__ Wv, const float* __restrict__ bv,
    float* __restrict__ Kk, float* __restrict__ Vv, int M)
{
    __shared__ __attribute__((aligned(16))) float xk[TILE][DIM];
    __shared__ __attribute__((aligned(16))) float xv[TILE][DIM];
    const int t = threadIdx.x;
    const int row0 = blockIdx.x * TILE;
    #pragma unroll
    for (int i = 0; i < (TILE * DIM) / 256; ++i) {
        int idx = t + i * 256;
        int r = idx >> 7, c = idx & 127;
        int gr = row0 + r;
        xk[r][c] = (gr < M) ? key[(size_t)gr * DIM + c] : 0.f;
        xv[r][c] = (gr < M) ? value[(size_t)gr * DIM + c] : 0.f;
    }
    __syncthreads();

    const int ty = t >> 5;
    const int tx = t & 31;
    const int c0 = tx * 4;

    float accK[4][4] = {{0}}, accV[4][4] = {{0}};

    for (int k4 = 0; k4 < DIM; k4 += 4) {
        float kv[4][4], vv[4][4];
        #pragma unroll
        for (int j = 0; j < 4; ++j) {
            *(float4*)&kv[j][0] = *(const float4*)&xk[ty * 4 + j][k4];
            *(float4*)&vv[j][0] = *(const float4*)&xv[ty * 4 + j][k4];
        }
        #pragma unroll
        for (int kk = 0; kk < 4; ++kk) {
            const float4 wk = *(const float4*)&Wk[(k4 + kk) * DIM + c0];
            const float4 wv = *(const float4*)&Wv[(k4 + kk) * DIM + c0];
            #pragma unroll
            for (int j = 0; j < 4; ++j) {
                const float a = kv[j][kk];
                const float b = vv[j][kk];
                accK[j][0] = fmaf(a, wk.x, accK[j][0]);
                accK[j][1] = fmaf(a, wk.y, accK[j][1]);
                accK[j][2] = fmaf(a, wk.z, accK[j][2]);
                accK[j][3] = fmaf(a, wk.w, accK[j][3]);
                accV[j][0] = fmaf(b, wv.x, accV[j][0]);
                accV[j][1] = fmaf(b, wv.y, accV[j][1]);
                accV[j][2] = fmaf(b, wv.z, accV[j][2]);
                accV[j][3] = fmaf(b, wv.w, accV[j][3]);
            }
        }
    }

    float bk4[4], bv4[4];
    *(float4*)bk4 = *(const float4*)&bk[c0];
    *(float4*)bv4 = *(const float4*)&bv[c0];
    #pragma unroll
    for (int j = 0; j < 4; ++j) {
        const int gr = row0 + ty * 4 + j;
        if (gr < M) {
            *(float4*)&Kk[(size_t)gr * DIM + c0] = make_float4(
                accK[j][0] + bk4[0], accK[j][1] + bk4[1], accK[j][2] + bk4[2], accK[j][3] + bk4[3]);
            *(float4*)&Vv[(size_t)gr * DIM + c0] = make_float4(
                accV[j][0] + bv4[0], accV[j][1] + bv4[1], accV[j][2] + bv4[2], accV[j][3] + bv4[3]);
        }
    }
}

// ------------------------------------------------------------------
// CSR build: histogram, hierarchical exclusive scan, fill.
// ------------------------------------------------------------------
__global__ void hist_kernel(const int* __restrict__ qidx, int* __restrict__ counts, int E)
{
    for (int e = blockIdx.x * blockDim.x + threadIdx.x; e < E; e += gridDim.x * blockDim.x)
        atomicAdd(&counts[qidx[e]], 1);
}

__global__ __launch_bounds__(256) void scan1_kernel(const int* __restrict__ counts,
                                                    int* __restrict__ bsum, int N)
{
    __shared__ int sh[256];
    int i = blockIdx.x * 256 + threadIdx.x;
    sh[threadIdx.x] = (i < N) ? counts[i] : 0;
    __syncthreads();
    #pragma unroll
    for (int off = 128; off; off >>= 1) {
        if (threadIdx.x < off) sh[threadIdx.x] += sh[threadIdx.x + off];
        __syncthreads();
    }
    if (threadIdx.x == 0) bsum[blockIdx.x] = sh[0];
}

__global__ __launch_bounds__(256) void scan2_kernel(const int* __restrict__ bsum,
                                                    int* __restrict__ boff, int B)
{
    int t = threadIdx.x;
    if (B > 256) { // fallback (not expected for this problem size)
        if (t == 0) { int run = 0; for (int i = 0; i < B; ++i) { int v = bsum[i]; boff[i] = run; run += v; } }
        return;
    }
    __shared__ int sh[256];
    int v = (t < B) ? bsum[t] : 0;
    sh[t] = v;
    __syncthreads();
    for (int off = 1; off < 256; off <<= 1) {
        int x = (t >= off) ? sh[t - off] : 0;
        __syncthreads();
        sh[t] += x;
        __syncthreads();
    }
    if (t < B) boff[t] = sh[t] - v;  // exclusive
}

__global__ __launch_bounds__(256) void scan3_kernel(const int* __restrict__ counts,
                                                    const int* __restrict__ boff,
                                                    int* __restrict__ offsets,
                                                    int* __restrict__ cursor,
                                                    int N, int E)
{
    __shared__ int sh[256];
    int t = threadIdx.x;
    int i = blockIdx.x * 256 + t;
    int v = (i < N) ? counts[i] : 0;
    sh[t] = v;
    __syncthreads();
    for (int off = 1; off < 256; off <<= 1) {
        int x = (t >= off) ? sh[t - off] : 0;
        __syncthreads();
        sh[t] += x;
        __syncthreads();
    }
    int base = boff[blockIdx.x];
    if (i < N) {
        int o = base + sh[t] - v;
        offsets[i] = o;
        cursor[i] = o;
    }
    if (i == 0) offsets[N] = E;
}

__global__ void fill_kernel(const int* __restrict__ qidx, int* __restrict__ cursor,
                            int* __restrict__ eid, int E)
{
    for (int e = blockIdx.x * blockDim.x + threadIdx.x; e < E; e += gridDim.x * blockDim.x) {
        int q = qidx[e];
        int pos = atomicAdd(&cursor[q], 1);
        eid[pos] = e;
    }
}

// ------------------------------------------------------------------
// Node-centric edge aggregation with online softmax.
// One wave per query node; lane holds dims 2*lane, 2*lane+1; head = lane/8.
// msgn = (exp_qq*Vq + sum_e exp_e*Vv[ki]) / denom
// ------------------------------------------------------------------
__global__ __launch_bounds__(256) void edge_agg_kernel(
    const float* __restrict__ Qq, const float* __restrict__ Vq,
    const float* __restrict__ attnqq,
    const float* __restrict__ Kk, const float* __restrict__ Vv,
    const int* __restrict__ key_idx, const int* __restrict__ eid,
    const int* __restrict__ offsets,
    const float* __restrict__ avec, const float* __restrict__ alpha_p,
    float* __restrict__ msgn, int N)
{
    const int wid = threadIdx.x >> 6;
    const int lane = threadIdx.x & 63;
    const int n = blockIdx.x * 4 + wid;
    if (n >= N) return;

    const float al = alpha_p[0];
    const int d0 = lane * 2;
    const int h = lane >> 3;

    const float2 qq = *(const float2*)&Qq[(size_t)n * DIM + d0];
    const float2 vq = *(const float2*)&Vq[(size_t)n * DIM + d0];
    const float2 av = *(const float2*)&avec[d0];

    float m = attnqq[(size_t)n * NH + h];   // self score (init max)
    float den = 1.f;                        // exp(self - m) = 1
    float accx = vq.x, accy = vq.y;

    const int p0 = offsets[n], p1 = offsets[n + 1];
    for (int p = p0; p < p1; ++p) {
        const int e = eid[p];
        const int ki = key_idx[e];
        const float2 kk = *(const float2*)&Kk[(size_t)ki * DIM + d0];
        float s = av.x * prelu_f(qq.x + kk.x, al) + av.y * prelu_f(qq.y + kk.y, al);
        s += __shfl_xor(s, 1, 8);
        s += __shfl_xor(s, 2, 8);
        s += __shfl_xor(s, 4, 8);
        const float2 vv = *(const float2*)&Vv[(size_t)ki * DIM + d0];
        const float nm = fmaxf(m, s);
        const float c = __expf(m - nm);
        const float w = __expf(s - nm);
        den = den * c + w;
        accx = accx * c + w * vv.x;
        accy = accy * c + w * vv.y;
        m = nm;
    }
    const float inv = 1.f / den;
    *(float2*)&msgn[(size_t)n * DIM + d0] = make_float2(accx * inv, accy * inv);
}

// ------------------------------------------------------------------
// Output projection + residual + LayerNorm.
// ------------------------------------------------------------------
__global__ __launch_bounds__(256) void out_ln_kernel(
    const float* __restrict__ msgn, const float* __restrict__ Wp,
    const float* __restrict__ bp, const float* __restrict__ query,
    const float* __restrict__ gamma, const float* __restrict__ beta,
    float* __restrict__ out, int N)
{
    __shared__ __attribute__((aligned(16))) float xs[TILE][DIM];
    __shared__ __attribute__((aligned(16))) float ys[TILE][DIM];
    const int t = threadIdx.x;
    const int row0 = blockIdx.x * TILE;
    #pragma unroll
    for (int i = 0; i < (TILE * DIM) / 256; ++i) {
        int idx = t + i * 256;
        int r = idx >> 7, c = idx & 127;
        int gr = row0 + r;
        xs[r][c] = (gr < N) ? msgn[(size_t)gr * DIM + c] : 0.f;
    }
    __syncthreads();

    const int ty = t >> 5;
    const int tx = t & 31;
    const int c0 = tx * 4;

    float acc[4][4] = {{0}};
    for (int k4 = 0; k4 < DIM; k4 += 4) {
        float xv[4][4];
        #pragma unroll
        for (int j = 0; j < 4; ++j)
            *(float4*)&xv[j][0] = *(const float4*)&xs[ty * 4 + j][k4];
        #pragma unroll
        for (int kk = 0; kk < 4; ++kk) {
            const float4 wp = *(const float4*)&Wp[(k4 + kk) * DIM + c0];
            #pragma unroll
            for (int j = 0; j < 4; ++j) {
                const float x = xv[j][kk];
                acc[j][0] = fmaf(x, wp.x, acc[j][0]);
                acc[j][1] = fmaf(x, wp.y, acc[j][1]);
                acc[j][2] = fmaf(x, wp.z, acc[j][2]);
                acc[j][3] = fmaf(x, wp.w, acc[j][3]);
            }
        }
    }
    float bp4[4];
    *(float4*)bp4 = *(const float4*)&bp[c0];
    #pragma unroll
    for (int j = 0; j < 4; ++j) {
        *(float4*)&ys[ty * 4 + j][c0] = make_float4(
            acc[j][0] + bp4[0], acc[j][1] + bp4[1], acc[j][2] + bp4[2], acc[j][3] + bp4[3]);
    }
    __syncthreads();

    // LayerNorm: 4 waves x 8 rows
    const int wid = t >> 6;
    const int lane = t & 63;
    for (int rr = 0; rr < 8; ++rr) {
        const int r = wid * 8 + rr;
        const int gr = row0 + r;
        if (gr >= N) break;
        const float y1 = ys[r][lane], y2 = ys[r][lane + 64];
        const float q1 = query[(size_t)gr * DIM + lane];
        const float q2 = query[(size_t)gr * DIM + lane + 64];
        const float r1 = y1 + q1, r2 = y2 + q2;
        float s = r1 + r2;
        float ss = r1 * r1 + r2 * r2;
        #pragma unroll
        for (int off = 32; off; off >>= 1) {
            s += __shfl_xor(s, off);
            ss += __shfl_xor(ss, off);
        }
        const float mu = s * (1.f / DIM);
        const float var = ss * (1.f / DIM) - mu * mu;
        const float rstd = rsqrtf(var + LN_EPS);
        out[(size_t)gr * DIM + lane] = gamma[lane] * (r1 - mu) * rstd + beta[lane];
        out[(size_t)gr * DIM + lane + 64] = gamma[lane + 64] * (r2 - mu) * rstd + beta[lane + 64];
    }
}

// ------------------------------------------------------------------
extern "C" void kernel_launch(void* const* d_in, const int* in_sizes, int n_in,
                              void* d_out, int out_size, void* d_ws, size_t ws_size,
                              hipStream_t stream) {
    const float* query = (const float*)d_in[0];
    const float* key   = (const float*)d_in[1];
    const float* value = (const float*)d_in[2];
    const int* query_idx = (const int*)d_in[3];
    const int* key_idx   = (const int*)d_in[4];
    const float* Wq = (const float*)d_in[5];
    const float* bq = (const float*)d_in[6];
    const float* Wk = (const float*)d_in[7];
    const float* bk = (const float*)d_in[8];
    const float* Wv = (const float*)d_in[9];
    const float* bv = (const float*)d_in[10];
    const float* Wp = (const float*)d_in[11];
    const float* bp = (const float*)d_in[12];
    const float* avec  = (const float*)d_in[13];
    const float* alpha = (const float*)d_in[14];
    const float* gamma = (const float*)d_in[15];
    const float* beta  = (const float*)d_in[16];
    float* out = (float*)d_out;

    const int N = in_sizes[0] / DIM;
    const int M = in_sizes[1] / DIM;
    const int E = in_sizes[3];

    // workspace layout
    float* f = (float*)d_ws;
    float* Qq = f;      f += (size_t)N * DIM;
    float* Vq = f;      f += (size_t)N * DIM;
    float* Kk = f;      f += (size_t)M * DIM;
    float* Vv = f;      f += (size_t)M * DIM;
    float* attnqq = f;  f += (size_t)N * NH;
    float* msgn = f;    f += (size_t)N * DIM;
    int* ip = (int*)f;
    int* counts  = ip;  ip += N;
    int* offsets = ip;  ip += N + 1;
    int* cursor  = ip;  ip += N;
    int* bsum    = ip;  ip += 4096;
    int* boff    = ip;  ip += 4096;
    int* eid     = ip;  ip += E;

    const int B = (N + 255) / 256;

    hipMemsetAsync(counts, 0, (size_t)N * sizeof(int), stream);

    proj_query_kernel<<<(N + TILE - 1) / TILE, 256, 0, stream>>>(
        query, Wq, bq, Wk, bk, Wv, bv, avec, alpha, Qq, Vq, attnqq, N);
    proj_kv_kernel<<<(M + TILE - 1) / TILE, 256, 0, stream>>>(
        key, value, Wk, bk, Wv, bv, Kk, Vv, M);

    hist_kernel<<<1024, 256, 0, stream>>>(query_idx, counts, E);
    scan1_kernel<<<B, 256, 0, stream>>>(counts, bsum, N);
    scan2_kernel<<<1, 256, 0, stream>>>(bsum, boff, B);
    scan3_kernel<<<B, 256, 0, stream>>>(counts, boff, offsets, cursor, N, E);
    fill_kernel<<<1024, 256, 0, stream>>>(query_idx, cursor, eid, E);

    edge_agg_kernel<<<(N + 3) / 4, 256, 0, stream>>>(
        Qq, Vq, attnqq, Kk, Vv, key_idx, eid, offsets, avec, alpha, msgn, N);

    out_ln_kernel<<<(N + TILE - 1) / TILE, 256, 0, stream>>>(
        msgn, Wp, bp, query, gamma, beta, out, N);
}

// Round 2
// 249.908 us; speedup vs baseline: 1.7580x; 1.7580x over previous
//
#include <hip/hip_runtime.h>
#include <math.h>

#define DIM 128
#define NH 8
#define LN_EPS 1e-5f

using bf16x8 = __attribute__((ext_vector_type(8))) short;
using f32x4  = __attribute__((ext_vector_type(4))) float;

__device__ __forceinline__ float prelu_f(float x, float al) { return x >= 0.f ? x : al * x; }

__device__ __forceinline__ short f2bf(float f) {
    unsigned u = __float_as_uint(f);
    unsigned r = (u + 0x7fffu + ((u >> 16) & 1u)) >> 16;
    return (short)r;
}
__device__ __forceinline__ float bf2f(unsigned short h) { return __uint_as_float(((unsigned)h) << 16); }

// ------------------------------------------------------------------
// Pack 4 weight matrices (128x128 f32, row-major W[k][n]) into
// MFMA B-fragment order, bf16:  P[((ks*8+ct)*64+lane)*8 + r] =
//   bf16(W[(ks*32 + (lane>>4)*8 + r)][ct*16 + (lane&15)])
// ------------------------------------------------------------------
__global__ __launch_bounds__(256) void pack_w_kernel(
    const float* __restrict__ W0, const float* __restrict__ W1,
    const float* __restrict__ W2, const float* __restrict__ W3,
    short* __restrict__ P0, short* __restrict__ P1,
    short* __restrict__ P2, short* __restrict__ P3)
{
    const int id = blockIdx.x * 256 + threadIdx.x;   // 8192 total
    const int mat = id >> 11;
    const int rem = id & 2047;
    const int ks = rem >> 9;
    const int ct = (rem >> 6) & 7;
    const int lane = rem & 63;
    const int lr = lane & 15, lg = lane >> 4;
    const float* W = mat == 0 ? W0 : mat == 1 ? W1 : mat == 2 ? W2 : W3;
    short* P = mat == 0 ? P0 : mat == 1 ? P1 : mat == 2 ? P2 : P3;
    short v[8];
    #pragma unroll
    for (int r = 0; r < 8; ++r)
        v[r] = f2bf(W[(ks * 32 + lg * 8 + r) * DIM + ct * 16 + lr]);
    *(bf16x8*)&P[(size_t)((ks * 8 + ct) * 64 + lane) * 8] = *(bf16x8*)v;
}

// ------------------------------------------------------------------
// Query projection via MFMA: Qq=q@Wq+bq (f32), Vq=q@Wv+bv (f32),
// attnqq[n,h]=sum_d a*prelu(Qq+Kq). One wave per 16 rows.
// A-frag: lane holds row (lane&15), k = ks*32+(lane>>4)*8+j.
// D: col = ct*16+(lane&15), row = (lane>>4)*4 + r.
// ------------------------------------------------------------------
__global__ __launch_bounds__(256) void proj_query_mfma(
    const float* __restrict__ query,
    const short* __restrict__ Wqp, const short* __restrict__ Wkp, const short* __restrict__ Wvp,
    const float* __restrict__ bq, const float* __restrict__ bk, const float* __restrict__ bv,
    const float* __restrict__ avec, const float* __restrict__ alpha_p,
    float* __restrict__ Qq, float* __restrict__ Vq, float* __restrict__ attnqq, int N)
{
    const int wid = threadIdx.x >> 6, lane = threadIdx.x & 63;
    const int row0 = (blockIdx.x * 4 + wid) * 16;
    if (row0 >= N) return;
    const int lr = lane & 15, lg = lane >> 4;

    bf16x8 afrag[4];
    const int arow = row0 + lr;
    const bool rowok = arow < N;
    #pragma unroll
    for (int ks = 0; ks < 4; ++ks) {
        float t[8] = {0.f,0.f,0.f,0.f,0.f,0.f,0.f,0.f};
        if (rowok) {
            *(float4*)&t[0] = *(const float4*)&query[(size_t)arow * DIM + ks * 32 + lg * 8];
            *(float4*)&t[4] = *(const float4*)&query[(size_t)arow * DIM + ks * 32 + lg * 8 + 4];
        }
        bf16x8 a;
        #pragma unroll
        for (int j = 0; j < 8; ++j) a[j] = f2bf(t[j]);
        afrag[ks] = a;
    }

    f32x4 accQ[8], accK[8], accV[8];
    #pragma unroll
    for (int ct = 0; ct < 8; ++ct) { accQ[ct] = (f32x4)0.f; accK[ct] = (f32x4)0.f; accV[ct] = (f32x4)0.f; }

    #pragma unroll
    for (int ks = 0; ks < 4; ++ks) {
        #pragma unroll
        for (int ct = 0; ct < 8; ++ct) {
            const size_t bo = (size_t)((ks * 8 + ct) * 64 + lane) * 8;
            const bf16x8 bq_ = *(const bf16x8*)&Wqp[bo];
            const bf16x8 bk_ = *(const bf16x8*)&Wkp[bo];
            const bf16x8 bv_ = *(const bf16x8*)&Wvp[bo];
            accQ[ct] = __builtin_amdgcn_mfma_f32_16x16x32_bf16(afrag[ks], bq_, accQ[ct], 0, 0, 0);
            accK[ct] = __builtin_amdgcn_mfma_f32_16x16x32_bf16(afrag[ks], bk_, accK[ct], 0, 0, 0);
            accV[ct] = __builtin_amdgcn_mfma_f32_16x16x32_bf16(afrag[ks], bv_, accV[ct], 0, 0, 0);
        }
    }

    const float al = alpha_p[0];
    #pragma unroll
    for (int ct = 0; ct < 8; ++ct) {
        const int col = ct * 16 + lr;
        const float bqv = bq[col], bkv = bk[col], bvv = bv[col], av = avec[col];
        #pragma unroll
        for (int r = 0; r < 4; ++r) {
            const int grow = row0 + lg * 4 + r;
            const float qv = accQ[ct][r] + bqv;
            const float kv = accK[ct][r] + bkv;
            const float vv = accV[ct][r] + bvv;
            if (grow < N) {
                Qq[(size_t)grow * DIM + col] = qv;
                Vq[(size_t)grow * DIM + col] = vv;
            }
            float part = av * prelu_f(qv + kv, al);
            part += __shfl_xor(part, 1, 16);
            part += __shfl_xor(part, 2, 16);
            part += __shfl_xor(part, 4, 16);
            part += __shfl_xor(part, 8, 16);
            if (lr == 0 && grow < N) attnqq[(size_t)grow * NH + ct] = part;
        }
    }
}

// ------------------------------------------------------------------
// KV projection via MFMA: Kk=key@Wk+bk, Vv=value@Wv+bv, stored bf16.
// ------------------------------------------------------------------
__global__ __launch_bounds__(256) void proj_kv_mfma(
    const float* __restrict__ key, const float* __restrict__ value,
    const short* __restrict__ Wkp, const short* __restrict__ Wvp,
    const float* __restrict__ bk, const float* __restrict__ bv,
    short* __restrict__ Kk16, short* __restrict__ Vv16, int M)
{
    const int wid = threadIdx.x >> 6, lane = threadIdx.x & 63;
    const int row0 = (blockIdx.x * 4 + wid) * 16;
    if (row0 >= M) return;
    const int lr = lane & 15, lg = lane >> 4;

    bf16x8 afK[4], afV[4];
    const int arow = row0 + lr;
    const bool rowok = arow < M;
    #pragma unroll
    for (int ks = 0; ks < 4; ++ks) {
        float tk[8] = {0.f,0.f,0.f,0.f,0.f,0.f,0.f,0.f};
        float tv[8] = {0.f,0.f,0.f,0.f,0.f,0.f,0.f,0.f};
        if (rowok) {
            *(float4*)&tk[0] = *(const float4*)&key[(size_t)arow * DIM + ks * 32 + lg * 8];
            *(float4*)&tk[4] = *(const float4*)&key[(size_t)arow * DIM + ks * 32 + lg * 8 + 4];
            *(float4*)&tv[0] = *(const float4*)&value[(size_t)arow * DIM + ks * 32 + lg * 8];
            *(float4*)&tv[4] = *(const float4*)&value[(size_t)arow * DIM + ks * 32 + lg * 8 + 4];
        }
        bf16x8 a, b;
        #pragma unroll
        for (int j = 0; j < 8; ++j) { a[j] = f2bf(tk[j]); b[j] = f2bf(tv[j]); }
        afK[ks] = a; afV[ks] = b;
    }

    f32x4 accK[8], accV[8];
    #pragma unroll
    for (int ct = 0; ct < 8; ++ct) { accK[ct] = (f32x4)0.f; accV[ct] = (f32x4)0.f; }

    #pragma unroll
    for (int ks = 0; ks < 4; ++ks) {
        #pragma unroll
        for (int ct = 0; ct < 8; ++ct) {
            const size_t bo = (size_t)((ks * 8 + ct) * 64 + lane) * 8;
            const bf16x8 bk_ = *(const bf16x8*)&Wkp[bo];
            const bf16x8 bv_ = *(const bf16x8*)&Wvp[bo];
            accK[ct] = __builtin_amdgcn_mfma_f32_16x16x32_bf16(afK[ks], bk_, accK[ct], 0, 0, 0);
            accV[ct] = __builtin_amdgcn_mfma_f32_16x16x32_bf16(afV[ks], bv_, accV[ct], 0, 0, 0);
        }
    }

    #pragma unroll
    for (int ct = 0; ct < 8; ++ct) {
        const int col = ct * 16 + lr;
        const float bkv = bk[col], bvv = bv[col];
        #pragma unroll
        for (int r = 0; r < 4; ++r) {
            const int grow = row0 + lg * 4 + r;
            if (grow < M) {
                Kk16[(size_t)grow * DIM + col] = f2bf(accK[ct][r] + bkv);
                Vv16[(size_t)grow * DIM + col] = f2bf(accV[ct][r] + bvv);
            }
        }
    }
}

// ------------------------------------------------------------------
// CSR build
// ------------------------------------------------------------------
__global__ void hist_kernel(const int* __restrict__ qidx, int* __restrict__ counts, int E)
{
    for (int e = blockIdx.x * blockDim.x + threadIdx.x; e < E; e += gridDim.x * blockDim.x)
        atomicAdd(&counts[qidx[e]], 1);
}

__global__ __launch_bounds__(256) void scan1_kernel(const int* __restrict__ counts,
                                                    int* __restrict__ bsum, int N)
{
    __shared__ int sh[256];
    int i = blockIdx.x * 256 + threadIdx.x;
    sh[threadIdx.x] = (i < N) ? counts[i] : 0;
    __syncthreads();
    #pragma unroll
    for (int off = 128; off; off >>= 1) {
        if (threadIdx.x < off) sh[threadIdx.x] += sh[threadIdx.x + off];
        __syncthreads();
    }
    if (threadIdx.x == 0) bsum[blockIdx.x] = sh[0];
}

__global__ __launch_bounds__(256) void scan2_kernel(const int* __restrict__ bsum,
                                                    int* __restrict__ boff, int B)
{
    int t = threadIdx.x;
    if (B > 256) {
        if (t == 0) { int run = 0; for (int i = 0; i < B; ++i) { int v = bsum[i]; boff[i] = run; run += v; } }
        return;
    }
    __shared__ int sh[256];
    int v = (t < B) ? bsum[t] : 0;
    sh[t] = v;
    __syncthreads();
    for (int off = 1; off < 256; off <<= 1) {
        int x = (t >= off) ? sh[t - off] : 0;
        __syncthreads();
        sh[t] += x;
        __syncthreads();
    }
    if (t < B) boff[t] = sh[t] - v;
}

__global__ __launch_bounds__(256) void scan3_kernel(const int* __restrict__ counts,
                                                    const int* __restrict__ boff,
                                                    int* __restrict__ offsets,
                                                    int* __restrict__ cursor,
                                                    int N, int E)
{
    __shared__ int sh[256];
    int t = threadIdx.x;
    int i = blockIdx.x * 256 + t;
    int v = (i < N) ? counts[i] : 0;
    sh[t] = v;
    __syncthreads();
    for (int off = 1; off < 256; off <<= 1) {
        int x = (t >= off) ? sh[t - off] : 0;
        __syncthreads();
        sh[t] += x;
        __syncthreads();
    }
    int base = boff[blockIdx.x];
    if (i < N) {
        int o = base + sh[t] - v;
        offsets[i] = o;
        cursor[i] = o;
    }
    if (i == 0) offsets[N] = E;
}

// stores key_idx (not edge id) to remove one indirection in edge_agg
__global__ void fill_kernel(const int* __restrict__ qidx, const int* __restrict__ kidx,
                            int* __restrict__ cursor, int* __restrict__ ksorted, int E)
{
    for (int e = blockIdx.x * blockDim.x + threadIdx.x; e < E; e += gridDim.x * blockDim.x) {
        int q = qidx[e];
        int pos = atomicAdd(&cursor[q], 1);
        ksorted[pos] = kidx[e];
    }
}

// ------------------------------------------------------------------
// Node-centric online-softmax aggregation; bf16 K/V gathers.
// One wave per node; lane holds dims 2*lane..2*lane+1; head = lane/8.
// ------------------------------------------------------------------
__global__ __launch_bounds__(256) void edge_agg_kernel(
    const float* __restrict__ Qq, const float* __restrict__ Vq,
    const float* __restrict__ attnqq,
    const short* __restrict__ Kk16, const short* __restrict__ Vv16,
    const int* __restrict__ ksorted, const int* __restrict__ offsets,
    const float* __restrict__ avec, const float* __restrict__ alpha_p,
    short* __restrict__ msgn16, int N)
{
    const int wid = threadIdx.x >> 6;
    const int lane = threadIdx.x & 63;
    const int n = blockIdx.x * 4 + wid;
    if (n >= N) return;

    const float al = alpha_p[0];
    const int d0 = lane * 2;
    const int h = lane >> 3;

    const float2 qq = *(const float2*)&Qq[(size_t)n * DIM + d0];
    const float2 vq = *(const float2*)&Vq[(size_t)n * DIM + d0];
    const float2 av = *(const float2*)&avec[d0];

    float m = attnqq[(size_t)n * NH + h];
    float den = 1.f;
    float accx = vq.x, accy = vq.y;

    const int p0 = offsets[n], p1 = offsets[n + 1];
    int ki = (p0 < p1) ? ksorted[p0] : 0;
    for (int p = p0; p < p1; ++p) {
        const unsigned kk2 = *(const unsigned*)&Kk16[(size_t)ki * DIM + d0];
        const unsigned vv2 = *(const unsigned*)&Vv16[(size_t)ki * DIM + d0];
        const int ki_n = (p + 1 < p1) ? ksorted[p + 1] : 0;
        float s = av.x * prelu_f(qq.x + bf2f((unsigned short)(kk2 & 0xffffu)), al)
                + av.y * prelu_f(qq.y + bf2f((unsigned short)(kk2 >> 16)), al);
        s += __shfl_xor(s, 1, 8);
        s += __shfl_xor(s, 2, 8);
        s += __shfl_xor(s, 4, 8);
        const float nm = fmaxf(m, s);
        const float c = __expf(m - nm);
        const float w = __expf(s - nm);
        den = den * c + w;
        accx = accx * c + w * bf2f((unsigned short)(vv2 & 0xffffu));
        accy = accy * c + w * bf2f((unsigned short)(vv2 >> 16));
        m = nm;
        ki = ki_n;
    }
    const float inv = 1.f / den;
    const unsigned o = (unsigned)(unsigned short)f2bf(accx * inv)
                     | ((unsigned)(unsigned short)f2bf(accy * inv) << 16);
    *(unsigned*)&msgn16[(size_t)n * DIM + d0] = o;
}

// ------------------------------------------------------------------
// Output projection (MFMA, bf16 A) + residual + LayerNorm.
// ------------------------------------------------------------------
__global__ __launch_bounds__(256) void out_ln_mfma(
    const short* __restrict__ msgn16, const short* __restrict__ Wpp,
    const float* __restrict__ bp, const float* __restrict__ query,
    const float* __restrict__ gamma, const float* __restrict__ beta,
    float* __restrict__ out, int N)
{
    __shared__ float ys[64][130];
    const int wid = threadIdx.x >> 6, lane = threadIdx.x & 63;
    const int rowbase = blockIdx.x * 64;
    const int row0 = rowbase + wid * 16;
    const int lr = lane & 15, lg = lane >> 4;

    if (row0 < N) {
        bf16x8 afrag[4];
        const int arow = row0 + lr;
        const bool rowok = arow < N;
        #pragma unroll
        for (int ks = 0; ks < 4; ++ks) {
            if (rowok)
                afrag[ks] = *(const bf16x8*)&msgn16[(size_t)arow * DIM + ks * 32 + lg * 8];
            else {
                bf16x8 z;
                #pragma unroll
                for (int j = 0; j < 8; ++j) z[j] = 0;
                afrag[ks] = z;
            }
        }
        f32x4 acc[8];
        #pragma unroll
        for (int ct = 0; ct < 8; ++ct) acc[ct] = (f32x4)0.f;
        #pragma unroll
        for (int ks = 0; ks < 4; ++ks) {
            #pragma unroll
            for (int ct = 0; ct < 8; ++ct) {
                const size_t bo = (size_t)((ks * 8 + ct) * 64 + lane) * 8;
                const bf16x8 b_ = *(const bf16x8*)&Wpp[bo];
                acc[ct] = __builtin_amdgcn_mfma_f32_16x16x32_bf16(afrag[ks], b_, acc[ct], 0, 0, 0);
            }
        }
        #pragma unroll
        for (int ct = 0; ct < 8; ++ct) {
            const int col = ct * 16 + lr;
            const float bpv = bp[col];
            #pragma unroll
            for (int r = 0; r < 4; ++r)
                ys[wid * 16 + lg * 4 + r][col] = acc[ct][r] + bpv;
        }
    }
    __syncthreads();

    for (int rr = 0; rr < 16; ++rr) {
        const int r = wid * 16 + rr;
        const int grow = rowbase + r;
        if (grow >= N) break;
        const float y1 = ys[r][lane], y2 = ys[r][lane + 64];
        const float q1 = query[(size_t)grow * DIM + lane];
        const float q2 = query[(size_t)grow * DIM + lane + 64];
        const float r1 = y1 + q1, r2 = y2 + q2;
        float s = r1 + r2;
        float ss = r1 * r1 + r2 * r2;
        #pragma unroll
        for (int off = 32; off; off >>= 1) {
            s += __shfl_xor(s, off);
            ss += __shfl_xor(ss, off);
        }
        const float mu = s * (1.f / DIM);
        const float var = ss * (1.f / DIM) - mu * mu;
        const float rstd = rsqrtf(var + LN_EPS);
        out[(size_t)grow * DIM + lane] = gamma[lane] * (r1 - mu) * rstd + beta[lane];
        out[(size_t)grow * DIM + lane + 64] = gamma[lane + 64] * (r2 - mu) * rstd + beta[lane + 64];
    }
}

// ------------------------------------------------------------------
extern "C" void kernel_launch(void* const* d_in, const int* in_sizes, int n_in,
                              void* d_out, int out_size, void* d_ws, size_t ws_size,
                              hipStream_t stream) {
    const float* query = (const float*)d_in[0];
    const float* key   = (const float*)d_in[1];
    const float* value = (const float*)d_in[2];
    const int* query_idx = (const int*)d_in[3];
    const int* key_idx   = (const int*)d_in[4];
    const float* Wq = (const float*)d_in[5];
    const float* bq = (const float*)d_in[6];
    const float* Wk = (const float*)d_in[7];
    const float* bk = (const float*)d_in[8];
    const float* Wv = (const float*)d_in[9];
    const float* bv = (const float*)d_in[10];
    const float* Wp = (const float*)d_in[11];
    const float* bp = (const float*)d_in[12];
    const float* avec  = (const float*)d_in[13];
    const float* alpha = (const float*)d_in[14];
    const float* gamma = (const float*)d_in[15];
    const float* beta  = (const float*)d_in[16];
    float* out = (float*)d_out;

    const int N = in_sizes[0] / DIM;
    const int M = in_sizes[1] / DIM;
    const int E = in_sizes[3];

    // workspace layout (all 16B aligned)
    float* f = (float*)d_ws;
    float* Qq = f;      f += (size_t)N * DIM;
    float* Vq = f;      f += (size_t)N * DIM;
    float* attnqq = f;  f += (size_t)N * NH;
    short* sp = (short*)f;
    short* Kk16 = sp;   sp += (size_t)M * DIM;
    short* Vv16 = sp;   sp += (size_t)M * DIM;
    short* msgn16 = sp; sp += (size_t)N * DIM;
    short* Wqp = sp;    sp += DIM * DIM;
    short* Wkp = sp;    sp += DIM * DIM;
    short* Wvp = sp;    sp += DIM * DIM;
    short* Wpp = sp;    sp += DIM * DIM;
    int* ip = (int*)(((size_t)sp + 15) & ~(size_t)15);
    int* counts  = ip;  ip += N;
    int* offsets = ip;  ip += N + 1;
    int* cursor  = ip;  ip += N;
    int* bsum    = ip;  ip += 4096;
    int* boff    = ip;  ip += 4096;
    int* ksorted = ip;  ip += E;

    const int B = (N + 255) / 256;

    hipMemsetAsync(counts, 0, (size_t)N * sizeof(int), stream);

    pack_w_kernel<<<32, 256, 0, stream>>>(Wq, Wk, Wv, Wp, Wqp, Wkp, Wvp, Wpp);

    proj_query_mfma<<<(N + 63) / 64, 256, 0, stream>>>(
        query, Wqp, Wkp, Wvp, bq, bk, bv, avec, alpha, Qq, Vq, attnqq, N);
    proj_kv_mfma<<<(M + 63) / 64, 256, 0, stream>>>(
        key, value, Wkp, Wvp, bk, bv, Kk16, Vv16, M);

    hist_kernel<<<1024, 256, 0, stream>>>(query_idx, counts, E);
    scan1_kernel<<<B, 256, 0, stream>>>(counts, bsum, N);
    scan2_kernel<<<1, 256, 0, stream>>>(bsum, boff, B);
    scan3_kernel<<<B, 256, 0, stream>>>(counts, boff, offsets, cursor, N, E);
    fill_kernel<<<1024, 256, 0, stream>>>(query_idx, key_idx, cursor, ksorted, E);

    edge_agg_kernel<<<(N + 3) / 4, 256, 0, stream>>>(
        Qq, Vq, attnqq, Kk16, Vv16, ksorted, offsets, avec, alpha, msgn16, N);

    out_ln_mfma<<<(N + 63) / 64, 256, 0, stream>>>(
        msgn16, Wpp, bp, query, gamma, beta, out, N);
}

// Round 3
// 241.776 us; speedup vs baseline: 1.8171x; 1.0336x over previous
//
#include <hip/hip_runtime.h>
#include <math.h>

#define DIM 128
#define NH 8
#define LN_EPS 1e-5f

using bf16x8 = __attribute__((ext_vector_type(8))) short;
using f32x4  = __attribute__((ext_vector_type(4))) float;

__device__ __forceinline__ float prelu_f(float x, float al) { return x >= 0.f ? x : al * x; }

__device__ __forceinline__ short f2bf(float f) {
    unsigned u = __float_as_uint(f);
    unsigned r = (u + 0x7fffu + ((u >> 16) & 1u)) >> 16;
    return (short)r;
}
__device__ __forceinline__ float bf2f(unsigned short h) { return __uint_as_float(((unsigned)h) << 16); }
__device__ __forceinline__ float bflo(unsigned u) { return __uint_as_float(u << 16); }
__device__ __forceinline__ float bfhi(unsigned u) { return __uint_as_float(u & 0xffff0000u); }

__device__ __forceinline__ float swz_xor1(float x) {
    return __int_as_float(__builtin_amdgcn_ds_swizzle(__float_as_int(x), 0x041F));
}
__device__ __forceinline__ float swz_xor2(float x) {
    return __int_as_float(__builtin_amdgcn_ds_swizzle(__float_as_int(x), 0x081F));
}
__device__ __forceinline__ float swz_xor4(float x) {
    return __int_as_float(__builtin_amdgcn_ds_swizzle(__float_as_int(x), 0x101F));
}

// ------------------------------------------------------------------
// Pack 4 weight matrices (128x128 f32, row-major W[k][n]) into
// MFMA B-fragment order, bf16.
// ------------------------------------------------------------------
__global__ __launch_bounds__(256) void pack_w_kernel(
    const float* __restrict__ W0, const float* __restrict__ W1,
    const float* __restrict__ W2, const float* __restrict__ W3,
    short* __restrict__ P0, short* __restrict__ P1,
    short* __restrict__ P2, short* __restrict__ P3)
{
    const int id = blockIdx.x * 256 + threadIdx.x;   // 8192 total
    const int mat = id >> 11;
    const int rem = id & 2047;
    const int ks = rem >> 9;
    const int ct = (rem >> 6) & 7;
    const int lane = rem & 63;
    const int lr = lane & 15, lg = lane >> 4;
    const float* W = mat == 0 ? W0 : mat == 1 ? W1 : mat == 2 ? W2 : W3;
    short* P = mat == 0 ? P0 : mat == 1 ? P1 : mat == 2 ? P2 : P3;
    short v[8];
    #pragma unroll
    for (int r = 0; r < 8; ++r)
        v[r] = f2bf(W[(ks * 32 + lg * 8 + r) * DIM + ct * 16 + lr]);
    *(bf16x8*)&P[(size_t)((ks * 8 + ct) * 64 + lane) * 8] = *(bf16x8*)v;
}

// ------------------------------------------------------------------
// Query projection via MFMA (Qq, Vq f32; attn_qq fused).
// ------------------------------------------------------------------
__global__ __launch_bounds__(256) void proj_query_mfma(
    const float* __restrict__ query,
    const short* __restrict__ Wqp, const short* __restrict__ Wkp, const short* __restrict__ Wvp,
    const float* __restrict__ bq, const float* __restrict__ bk, const float* __restrict__ bv,
    const float* __restrict__ avec, const float* __restrict__ alpha_p,
    float* __restrict__ Qq, float* __restrict__ Vq, float* __restrict__ attnqq, int N)
{
    const int wid = threadIdx.x >> 6, lane = threadIdx.x & 63;
    const int row0 = (blockIdx.x * 4 + wid) * 16;
    if (row0 >= N) return;
    const int lr = lane & 15, lg = lane >> 4;

    bf16x8 afrag[4];
    const int arow = row0 + lr;
    const bool rowok = arow < N;
    #pragma unroll
    for (int ks = 0; ks < 4; ++ks) {
        float t[8] = {0.f,0.f,0.f,0.f,0.f,0.f,0.f,0.f};
        if (rowok) {
            *(float4*)&t[0] = *(const float4*)&query[(size_t)arow * DIM + ks * 32 + lg * 8];
            *(float4*)&t[4] = *(const float4*)&query[(size_t)arow * DIM + ks * 32 + lg * 8 + 4];
        }
        bf16x8 a;
        #pragma unroll
        for (int j = 0; j < 8; ++j) a[j] = f2bf(t[j]);
        afrag[ks] = a;
    }

    f32x4 accQ[8], accK[8], accV[8];
    #pragma unroll
    for (int ct = 0; ct < 8; ++ct) { accQ[ct] = (f32x4)0.f; accK[ct] = (f32x4)0.f; accV[ct] = (f32x4)0.f; }

    #pragma unroll
    for (int ks = 0; ks < 4; ++ks) {
        #pragma unroll
        for (int ct = 0; ct < 8; ++ct) {
            const size_t bo = (size_t)((ks * 8 + ct) * 64 + lane) * 8;
            const bf16x8 bq_ = *(const bf16x8*)&Wqp[bo];
            const bf16x8 bk_ = *(const bf16x8*)&Wkp[bo];
            const bf16x8 bv_ = *(const bf16x8*)&Wvp[bo];
            accQ[ct] = __builtin_amdgcn_mfma_f32_16x16x32_bf16(afrag[ks], bq_, accQ[ct], 0, 0, 0);
            accK[ct] = __builtin_amdgcn_mfma_f32_16x16x32_bf16(afrag[ks], bk_, accK[ct], 0, 0, 0);
            accV[ct] = __builtin_amdgcn_mfma_f32_16x16x32_bf16(afrag[ks], bv_, accV[ct], 0, 0, 0);
        }
    }

    const float al = alpha_p[0];
    #pragma unroll
    for (int ct = 0; ct < 8; ++ct) {
        const int col = ct * 16 + lr;
        const float bqv = bq[col], bkv = bk[col], bvv = bv[col], av = avec[col];
        #pragma unroll
        for (int r = 0; r < 4; ++r) {
            const int grow = row0 + lg * 4 + r;
            const float qv = accQ[ct][r] + bqv;
            const float kv = accK[ct][r] + bkv;
            const float vv = accV[ct][r] + bvv;
            if (grow < N) {
                Qq[(size_t)grow * DIM + col] = qv;
                Vq[(size_t)grow * DIM + col] = vv;
            }
            float part = av * prelu_f(qv + kv, al);
            part += __shfl_xor(part, 1, 16);
            part += __shfl_xor(part, 2, 16);
            part += __shfl_xor(part, 4, 16);
            part += __shfl_xor(part, 8, 16);
            if (lr == 0 && grow < N) attnqq[(size_t)grow * NH + ct] = part;
        }
    }
}

// ------------------------------------------------------------------
// KV projection via MFMA; K and V interleaved per row: KV16[m][256]
// (first 128 = K, next 128 = V) so edge gathers share one base addr.
// ------------------------------------------------------------------
__global__ __launch_bounds__(256) void proj_kv_mfma(
    const float* __restrict__ key, const float* __restrict__ value,
    const short* __restrict__ Wkp, const short* __restrict__ Wvp,
    const float* __restrict__ bk, const float* __restrict__ bv,
    short* __restrict__ KV16, int M)
{
    const int wid = threadIdx.x >> 6, lane = threadIdx.x & 63;
    const int row0 = (blockIdx.x * 4 + wid) * 16;
    if (row0 >= M) return;
    const int lr = lane & 15, lg = lane >> 4;

    bf16x8 afK[4], afV[4];
    const int arow = row0 + lr;
    const bool rowok = arow < M;
    #pragma unroll
    for (int ks = 0; ks < 4; ++ks) {
        float tk[8] = {0.f,0.f,0.f,0.f,0.f,0.f,0.f,0.f};
        float tv[8] = {0.f,0.f,0.f,0.f,0.f,0.f,0.f,0.f};
        if (rowok) {
            *(float4*)&tk[0] = *(const float4*)&key[(size_t)arow * DIM + ks * 32 + lg * 8];
            *(float4*)&tk[4] = *(const float4*)&key[(size_t)arow * DIM + ks * 32 + lg * 8 + 4];
            *(float4*)&tv[0] = *(const float4*)&value[(size_t)arow * DIM + ks * 32 + lg * 8];
            *(float4*)&tv[4] = *(const float4*)&value[(size_t)arow * DIM + ks * 32 + lg * 8 + 4];
        }
        bf16x8 a, b;
        #pragma unroll
        for (int j = 0; j < 8; ++j) { a[j] = f2bf(tk[j]); b[j] = f2bf(tv[j]); }
        afK[ks] = a; afV[ks] = b;
    }

    f32x4 accK[8], accV[8];
    #pragma unroll
    for (int ct = 0; ct < 8; ++ct) { accK[ct] = (f32x4)0.f; accV[ct] = (f32x4)0.f; }

    #pragma unroll
    for (int ks = 0; ks < 4; ++ks) {
        #pragma unroll
        for (int ct = 0; ct < 8; ++ct) {
            const size_t bo = (size_t)((ks * 8 + ct) * 64 + lane) * 8;
            const bf16x8 bk_ = *(const bf16x8*)&Wkp[bo];
            const bf16x8 bv_ = *(const bf16x8*)&Wvp[bo];
            accK[ct] = __builtin_amdgcn_mfma_f32_16x16x32_bf16(afK[ks], bk_, accK[ct], 0, 0, 0);
            accV[ct] = __builtin_amdgcn_mfma_f32_16x16x32_bf16(afV[ks], bv_, accV[ct], 0, 0, 0);
        }
    }

    #pragma unroll
    for (int ct = 0; ct < 8; ++ct) {
        const int col = ct * 16 + lr;
        const float bkv = bk[col], bvv = bv[col];
        #pragma unroll
        for (int r = 0; r < 4; ++r) {
            const int grow = row0 + lg * 4 + r;
            if (grow < M) {
                KV16[(size_t)grow * 256 + col]       = f2bf(accK[ct][r] + bkv);
                KV16[(size_t)grow * 256 + 128 + col] = f2bf(accV[ct][r] + bvv);
            }
        }
    }
}

// ------------------------------------------------------------------
// CSR build
// ------------------------------------------------------------------
__global__ void hist_kernel(const int* __restrict__ qidx, int* __restrict__ counts, int E)
{
    for (int e = blockIdx.x * blockDim.x + threadIdx.x; e < E; e += gridDim.x * blockDim.x)
        atomicAdd(&counts[qidx[e]], 1);
}

__global__ __launch_bounds__(256) void scan1_kernel(const int* __restrict__ counts,
                                                    int* __restrict__ bsum, int N)
{
    __shared__ int sh[256];
    int i = blockIdx.x * 256 + threadIdx.x;
    sh[threadIdx.x] = (i < N) ? counts[i] : 0;
    __syncthreads();
    #pragma unroll
    for (int off = 128; off; off >>= 1) {
        if (threadIdx.x < off) sh[threadIdx.x] += sh[threadIdx.x + off];
        __syncthreads();
    }
    if (threadIdx.x == 0) bsum[blockIdx.x] = sh[0];
}

__global__ __launch_bounds__(256) void scan2_kernel(const int* __restrict__ bsum,
                                                    int* __restrict__ boff, int B)
{
    int t = threadIdx.x;
    if (B > 256) {
        if (t == 0) { int run = 0; for (int i = 0; i < B; ++i) { int v = bsum[i]; boff[i] = run; run += v; } }
        return;
    }
    __shared__ int sh[256];
    int v = (t < B) ? bsum[t] : 0;
    sh[t] = v;
    __syncthreads();
    for (int off = 1; off < 256; off <<= 1) {
        int x = (t >= off) ? sh[t - off] : 0;
        __syncthreads();
        sh[t] += x;
        __syncthreads();
    }
    if (t < B) boff[t] = sh[t] - v;
}

__global__ __launch_bounds__(256) void scan3_kernel(const int* __restrict__ counts,
                                                    const int* __restrict__ boff,
                                                    int* __restrict__ offsets,
                                                    int* __restrict__ cursor,
                                                    int N, int E)
{
    __shared__ int sh[256];
    int t = threadIdx.x;
    int i = blockIdx.x * 256 + t;
    int v = (i < N) ? counts[i] : 0;
    sh[t] = v;
    __syncthreads();
    for (int off = 1; off < 256; off <<= 1) {
        int x = (t >= off) ? sh[t - off] : 0;
        __syncthreads();
        sh[t] += x;
        __syncthreads();
    }
    int base = boff[blockIdx.x];
    if (i < N) {
        int o = base + sh[t] - v;
        offsets[i] = o;
        cursor[i] = o;
    }
    if (i == 0) offsets[N] = E;
}

__global__ void fill_kernel(const int* __restrict__ qidx, const int* __restrict__ kidx,
                            int* __restrict__ cursor, int* __restrict__ ksorted, int E)
{
    for (int e = blockIdx.x * blockDim.x + threadIdx.x; e < E; e += gridDim.x * blockDim.x) {
        int q = qidx[e];
        int pos = atomicAdd(&cursor[q], 1);
        ksorted[pos] = kidx[e];
    }
}

// ------------------------------------------------------------------
// Node-centric online-softmax aggregation, v3:
//  - ds_swizzle head reductions (no lane-addr calc)
//  - defer-max: rescale only when __any(s - m > 8) (softmax invariant)
//  - min/max-form prelu fused into FMA chain
//  - interleaved KV row: one base addr, V at +256B immediate
//  - 2-edge unroll to overlap swizzle latency
// ------------------------------------------------------------------
__global__ __launch_bounds__(256) void edge_agg_kernel(
    const float* __restrict__ Qq, const float* __restrict__ Vq,
    const float* __restrict__ attnqq,
    const short* __restrict__ KV16,
    const int* __restrict__ ksorted, const int* __restrict__ offsets,
    const float* __restrict__ avec, const float* __restrict__ alpha_p,
    short* __restrict__ msgn16, int N)
{
    const int wid = threadIdx.x >> 6;
    const int lane = threadIdx.x & 63;
    const int n = blockIdx.x * 4 + wid;
    if (n >= N) return;

    const float al = alpha_p[0];
    const int d0 = lane * 2;
    const int h = lane >> 3;

    const float2 qq = *(const float2*)&Qq[(size_t)n * DIM + d0];
    const float2 vq = *(const float2*)&Vq[(size_t)n * DIM + d0];
    const float2 av = *(const float2*)&avec[d0];
    const float2 ava = make_float2(av.x * al, av.y * al);

    float m = attnqq[(size_t)n * NH + h];
    float den = 1.f;
    float accx = vq.x, accy = vq.y;

    const int p0 = offsets[n], p1 = offsets[n + 1];
    int p = p0;

    // score for one gathered K row pair-of-dims, fused prelu
    #define SCORE(kk2, sout)                                                      \
        {                                                                         \
            const float x0 = qq.x + bflo(kk2);                                    \
            const float x1 = qq.y + bfhi(kk2);                                    \
            float s_ = fmaf(ava.y, fminf(x1, 0.f),                                \
                       fmaf(av.y, fmaxf(x1, 0.f),                                 \
                       fmaf(ava.x, fminf(x0, 0.f), av.x * fmaxf(x0, 0.f))));      \
            s_ += swz_xor1(s_);                                                   \
            s_ += swz_xor2(s_);                                                   \
            s_ += swz_xor4(s_);                                                   \
            sout = s_;                                                            \
        }

    if ((p1 - p0) & 1) {
        const int ki = ksorted[p];
        const unsigned kk2 = *(const unsigned*)&KV16[(size_t)ki * 256 + d0];
        const unsigned vv2 = *(const unsigned*)&KV16[(size_t)ki * 256 + 128 + d0];
        float s;
        SCORE(kk2, s);
        const float d = s - m;
        if (__any(d > 8.f)) {
            const float nm = fmaxf(m, s);
            const float c = __expf(m - nm);
            const float w = __expf(s - nm);
            den = den * c + w;
            accx = fmaf(accx, c, w * bflo(vv2));
            accy = fmaf(accy, c, w * bfhi(vv2));
            m = nm;
        } else {
            const float w = __expf(d);
            den += w;
            accx = fmaf(w, bflo(vv2), accx);
            accy = fmaf(w, bfhi(vv2), accy);
        }
        ++p;
    }

    for (; p < p1; p += 2) {
        const int ka = ksorted[p];
        const int kb = ksorted[p + 1];
        const unsigned kka = *(const unsigned*)&KV16[(size_t)ka * 256 + d0];
        const unsigned vva = *(const unsigned*)&KV16[(size_t)ka * 256 + 128 + d0];
        const unsigned kkb = *(const unsigned*)&KV16[(size_t)kb * 256 + d0];
        const unsigned vvb = *(const unsigned*)&KV16[(size_t)kb * 256 + 128 + d0];
        float sa, sb;
        SCORE(kka, sa);
        SCORE(kkb, sb);
        const float da = sa - m;
        const float db = sb - m;
        if (__any((da > 8.f) || (db > 8.f))) {
            float nm = fmaxf(m, sa);
            float c = __expf(m - nm);
            float w = __expf(sa - nm);
            den = den * c + w;
            accx = fmaf(accx, c, w * bflo(vva));
            accy = fmaf(accy, c, w * bfhi(vva));
            m = nm;
            nm = fmaxf(m, sb);
            c = __expf(m - nm);
            w = __expf(sb - nm);
            den = den * c + w;
            accx = fmaf(accx, c, w * bflo(vvb));
            accy = fmaf(accy, c, w * bfhi(vvb));
            m = nm;
        } else {
            const float wa = __expf(da);
            const float wb = __expf(db);
            den += wa + wb;
            accx = fmaf(wa, bflo(vva), fmaf(wb, bflo(vvb), accx));
            accy = fmaf(wa, bfhi(vva), fmaf(wb, bfhi(vvb), accy));
        }
    }
    #undef SCORE

    const float inv = 1.f / den;
    const unsigned o = (unsigned)(unsigned short)f2bf(accx * inv)
                     | ((unsigned)(unsigned short)f2bf(accy * inv) << 16);
    *(unsigned*)&msgn16[(size_t)n * DIM + d0] = o;
}

// ------------------------------------------------------------------
// Output projection (MFMA, bf16 A) + residual + LayerNorm.
// ------------------------------------------------------------------
__global__ __launch_bounds__(256) void out_ln_mfma(
    const short* __restrict__ msgn16, const short* __restrict__ Wpp,
    const float* __restrict__ bp, const float* __restrict__ query,
    const float* __restrict__ gamma, const float* __restrict__ beta,
    float* __restrict__ out, int N)
{
    __shared__ float ys[64][130];
    const int wid = threadIdx.x >> 6, lane = threadIdx.x & 63;
    const int rowbase = blockIdx.x * 64;
    const int row0 = rowbase + wid * 16;
    const int lr = lane & 15, lg = lane >> 4;

    if (row0 < N) {
        bf16x8 afrag[4];
        const int arow = row0 + lr;
        const bool rowok = arow < N;
        #pragma unroll
        for (int ks = 0; ks < 4; ++ks) {
            if (rowok)
                afrag[ks] = *(const bf16x8*)&msgn16[(size_t)arow * DIM + ks * 32 + lg * 8];
            else {
                bf16x8 z;
                #pragma unroll
                for (int j = 0; j < 8; ++j) z[j] = 0;
                afrag[ks] = z;
            }
        }
        f32x4 acc[8];
        #pragma unroll
        for (int ct = 0; ct < 8; ++ct) acc[ct] = (f32x4)0.f;
        #pragma unroll
        for (int ks = 0; ks < 4; ++ks) {
            #pragma unroll
            for (int ct = 0; ct < 8; ++ct) {
                const size_t bo = (size_t)((ks * 8 + ct) * 64 + lane) * 8;
                const bf16x8 b_ = *(const bf16x8*)&Wpp[bo];
                acc[ct] = __builtin_amdgcn_mfma_f32_16x16x32_bf16(afrag[ks], b_, acc[ct], 0, 0, 0);
            }
        }
        #pragma unroll
        for (int ct = 0; ct < 8; ++ct) {
            const int col = ct * 16 + lr;
            const float bpv = bp[col];
            #pragma unroll
            for (int r = 0; r < 4; ++r)
                ys[wid * 16 + lg * 4 + r][col] = acc[ct][r] + bpv;
        }
    }
    __syncthreads();

    for (int rr = 0; rr < 16; ++rr) {
        const int r = wid * 16 + rr;
        const int grow = rowbase + r;
        if (grow >= N) break;
        const float y1 = ys[r][lane], y2 = ys[r][lane + 64];
        const float q1 = query[(size_t)grow * DIM + lane];
        const float q2 = query[(size_t)grow * DIM + lane + 64];
        const float r1 = y1 + q1, r2 = y2 + q2;
        float s = r1 + r2;
        float ss = r1 * r1 + r2 * r2;
        #pragma unroll
        for (int off = 32; off; off >>= 1) {
            s += __shfl_xor(s, off);
            ss += __shfl_xor(ss, off);
        }
        const float mu = s * (1.f / DIM);
        const float var = ss * (1.f / DIM) - mu * mu;
        const float rstd = rsqrtf(var + LN_EPS);
        out[(size_t)grow * DIM + lane] = gamma[lane] * (r1 - mu) * rstd + beta[lane];
        out[(size_t)grow * DIM + lane + 64] = gamma[lane + 64] * (r2 - mu) * rstd + beta[lane + 64];
    }
}

// ------------------------------------------------------------------
extern "C" void kernel_launch(void* const* d_in, const int* in_sizes, int n_in,
                              void* d_out, int out_size, void* d_ws, size_t ws_size,
                              hipStream_t stream) {
    const float* query = (const float*)d_in[0];
    const float* key   = (const float*)d_in[1];
    const float* value = (const float*)d_in[2];
    const int* query_idx = (const int*)d_in[3];
    const int* key_idx   = (const int*)d_in[4];
    const float* Wq = (const float*)d_in[5];
    const float* bq = (const float*)d_in[6];
    const float* Wk = (const float*)d_in[7];
    const float* bk = (const float*)d_in[8];
    const float* Wv = (const float*)d_in[9];
    const float* bv = (const float*)d_in[10];
    const float* Wp = (const float*)d_in[11];
    const float* bp = (const float*)d_in[12];
    const float* avec  = (const float*)d_in[13];
    const float* alpha = (const float*)d_in[14];
    const float* gamma = (const float*)d_in[15];
    const float* beta  = (const float*)d_in[16];
    float* out = (float*)d_out;

    const int N = in_sizes[0] / DIM;
    const int M = in_sizes[1] / DIM;
    const int E = in_sizes[3];

    // workspace layout (all 16B aligned)
    float* f = (float*)d_ws;
    float* Qq = f;      f += (size_t)N * DIM;
    float* Vq = f;      f += (size_t)N * DIM;
    float* attnqq = f;  f += (size_t)N * NH;
    short* sp = (short*)f;
    short* KV16 = sp;   sp += (size_t)M * 2 * DIM;
    short* msgn16 = sp; sp += (size_t)N * DIM;
    short* Wqp = sp;    sp += DIM * DIM;
    short* Wkp = sp;    sp += DIM * DIM;
    short* Wvp = sp;    sp += DIM * DIM;
    short* Wpp = sp;    sp += DIM * DIM;
    int* ip = (int*)(((size_t)sp + 15) & ~(size_t)15);
    int* counts  = ip;  ip += N;
    int* offsets = ip;  ip += N + 1;
    int* cursor  = ip;  ip += N;
    int* bsum    = ip;  ip += 4096;
    int* boff    = ip;  ip += 4096;
    int* ksorted = ip;  ip += E;

    const int B = (N + 255) / 256;

    hipMemsetAsync(counts, 0, (size_t)N * sizeof(int), stream);

    pack_w_kernel<<<32, 256, 0, stream>>>(Wq, Wk, Wv, Wp, Wqp, Wkp, Wvp, Wpp);

    proj_query_mfma<<<(N + 63) / 64, 256, 0, stream>>>(
        query, Wqp, Wkp, Wvp, bq, bk, bv, avec, alpha, Qq, Vq, attnqq, N);
    proj_kv_mfma<<<(M + 63) / 64, 256, 0, stream>>>(
        key, value, Wkp, Wvp, bk, bv, KV16, M);

    hist_kernel<<<1024, 256, 0, stream>>>(query_idx, counts, E);
    scan1_kernel<<<B, 256, 0, stream>>>(counts, bsum, N);
    scan2_kernel<<<1, 256, 0, stream>>>(bsum, boff, B);
    scan3_kernel<<<B, 256, 0, stream>>>(counts, boff, offsets, cursor, N, E);
    fill_kernel<<<1024, 256, 0, stream>>>(query_idx, key_idx, cursor, ksorted, E);

    edge_agg_kernel<<<(N + 3) / 4, 256, 0, stream>>>(
        Qq, Vq, attnqq, KV16, ksorted, offsets, avec, alpha, msgn16, N);

    out_ln_mfma<<<(N + 63) / 64, 256, 0, stream>>>(
        msgn16, Wpp, bp, query, gamma, beta, out, N);
}

// Round 4
// 228.371 us; speedup vs baseline: 1.9238x; 1.0587x over previous
//
#include <hip/hip_runtime.h>
#include <math.h>

#define DIM 128
#define NH 8
#define LN_EPS 1e-5f

using bf16x8 = __attribute__((ext_vector_type(8))) short;
using f32x4  = __attribute__((ext_vector_type(4))) float;

__device__ __forceinline__ float prelu_f(float x, float al) { return x >= 0.f ? x : al * x; }

__device__ __forceinline__ short f2bf(float f) {
    unsigned u = __float_as_uint(f);
    unsigned r = (u + 0x7fffu + ((u >> 16) & 1u)) >> 16;
    return (short)r;
}
__device__ __forceinline__ float bflo(unsigned u) { return __uint_as_float(u << 16); }
__device__ __forceinline__ float bfhi(unsigned u) { return __uint_as_float(u & 0xffff0000u); }

// packed f32x2 -> bf16x2 (RNE), single instruction
__device__ __forceinline__ unsigned cvt_pk_bf16(float lo, float hi) {
    unsigned r;
    asm("v_cvt_pk_bf16_f32 %0, %1, %2" : "=v"(r) : "v"(lo), "v"(hi));
    return r;
}

__device__ __forceinline__ float swz_xor1(float x) {
    return __int_as_float(__builtin_amdgcn_ds_swizzle(__float_as_int(x), 0x041F));
}
__device__ __forceinline__ float swz_xor2(float x) {
    return __int_as_float(__builtin_amdgcn_ds_swizzle(__float_as_int(x), 0x081F));
}
__device__ __forceinline__ float swz_xor4(float x) {
    return __int_as_float(__builtin_amdgcn_ds_swizzle(__float_as_int(x), 0x101F));
}
__device__ __forceinline__ float swz_xor8(float x) {
    return __int_as_float(__builtin_amdgcn_ds_swizzle(__float_as_int(x), 0x201F));
}

// ------------------------------------------------------------------
// Pack 4 weight matrices (128x128 f32, row-major W[k][n]) into
// MFMA B-fragment order, bf16.
// ------------------------------------------------------------------
__global__ __launch_bounds__(256) void pack_w_kernel(
    const float* __restrict__ W0, const float* __restrict__ W1,
    const float* __restrict__ W2, const float* __restrict__ W3,
    short* __restrict__ P0, short* __restrict__ P1,
    short* __restrict__ P2, short* __restrict__ P3)
{
    const int id = blockIdx.x * 256 + threadIdx.x;   // 8192 total
    const int mat = id >> 11;
    const int rem = id & 2047;
    const int ks = rem >> 9;
    const int ct = (rem >> 6) & 7;
    const int lane = rem & 63;
    const int lr = lane & 15, lg = lane >> 4;
    const float* W = mat == 0 ? W0 : mat == 1 ? W1 : mat == 2 ? W2 : W3;
    short* P = mat == 0 ? P0 : mat == 1 ? P1 : mat == 2 ? P2 : P3;
    short v[8];
    #pragma unroll
    for (int r = 0; r < 8; ++r)
        v[r] = f2bf(W[(ks * 32 + lg * 8 + r) * DIM + ct * 16 + lr]);
    *(bf16x8*)&P[(size_t)((ks * 8 + ct) * 64 + lane) * 8] = *(bf16x8*)v;
}

// ------------------------------------------------------------------
// Query projection via MFMA.  Outputs:
//   QV32[n][256] f32: Q row (cols 0..127), Vq row (cols 128..255)
//   attnqq[n][8]
// Epilogue goes through a per-wave LDS slab for coalesced stores.
// ------------------------------------------------------------------
__global__ __launch_bounds__(256) void proj_query_mfma(
    const float* __restrict__ query,
    const short* __restrict__ Wqp, const short* __restrict__ Wkp, const short* __restrict__ Wvp,
    const float* __restrict__ bq, const float* __restrict__ bk, const float* __restrict__ bv,
    const float* __restrict__ avec, const float* __restrict__ alpha_p,
    float* __restrict__ QV32, float* __restrict__ attnqq, int N)
{
    __shared__ float lds[4][16][130];
    const int wid = threadIdx.x >> 6, lane = threadIdx.x & 63;
    const int row0 = (blockIdx.x * 4 + wid) * 16;
    if (row0 >= N) return;
    const int lr = lane & 15, lg = lane >> 4;

    bf16x8 afrag[4];
    const int arow = row0 + lr;
    const bool rowok = arow < N;
    #pragma unroll
    for (int ks = 0; ks < 4; ++ks) {
        float t[8] = {0.f,0.f,0.f,0.f,0.f,0.f,0.f,0.f};
        if (rowok) {
            *(float4*)&t[0] = *(const float4*)&query[(size_t)arow * DIM + ks * 32 + lg * 8];
            *(float4*)&t[4] = *(const float4*)&query[(size_t)arow * DIM + ks * 32 + lg * 8 + 4];
        }
        bf16x8 a;
        #pragma unroll
        for (int j = 0; j < 8; ++j) a[j] = f2bf(t[j]);
        afrag[ks] = a;
    }

    f32x4 accQ[8], accK[8], accV[8];
    #pragma unroll
    for (int ct = 0; ct < 8; ++ct) { accQ[ct] = (f32x4)0.f; accK[ct] = (f32x4)0.f; accV[ct] = (f32x4)0.f; }

    #pragma unroll
    for (int ks = 0; ks < 4; ++ks) {
        #pragma unroll
        for (int ct = 0; ct < 8; ++ct) {
            const size_t bo = (size_t)((ks * 8 + ct) * 64 + lane) * 8;
            const bf16x8 bq_ = *(const bf16x8*)&Wqp[bo];
            const bf16x8 bk_ = *(const bf16x8*)&Wkp[bo];
            const bf16x8 bv_ = *(const bf16x8*)&Wvp[bo];
            accQ[ct] = __builtin_amdgcn_mfma_f32_16x16x32_bf16(afrag[ks], bq_, accQ[ct], 0, 0, 0);
            accK[ct] = __builtin_amdgcn_mfma_f32_16x16x32_bf16(afrag[ks], bk_, accK[ct], 0, 0, 0);
            accV[ct] = __builtin_amdgcn_mfma_f32_16x16x32_bf16(afrag[ks], bv_, accV[ct], 0, 0, 0);
        }
    }

    const float al = alpha_p[0];
    // attnqq + stage Q into LDS
    #pragma unroll
    for (int ct = 0; ct < 8; ++ct) {
        const int col = ct * 16 + lr;
        const float bqv = bq[col], bkv = bk[col], av = avec[col];
        #pragma unroll
        for (int r = 0; r < 4; ++r) {
            const int grow = row0 + lg * 4 + r;
            const float qv = accQ[ct][r] + bqv;
            const float kv = accK[ct][r] + bkv;
            lds[wid][lg * 4 + r][col] = qv;
            float part = av * prelu_f(qv + kv, al);
            part += swz_xor1(part);
            part += swz_xor2(part);
            part += swz_xor4(part);
            part += swz_xor8(part);
            if (lr == 0 && grow < N) attnqq[(size_t)grow * NH + ct] = part;
        }
    }
    // coalesced Q stores (dwordx2 per lane, 512B per row per wave)
    const int cl = lane * 2;
    #pragma unroll
    for (int rr = 0; rr < 16; ++rr) {
        const int grow = row0 + rr;
        if (grow < N)
            *(float2*)&QV32[(size_t)grow * 256 + cl] = *(const float2*)&lds[wid][rr][cl];
    }
    // stage V, coalesced V stores
    #pragma unroll
    for (int ct = 0; ct < 8; ++ct) {
        const int col = ct * 16 + lr;
        const float bvv = bv[col];
        #pragma unroll
        for (int r = 0; r < 4; ++r)
            lds[wid][lg * 4 + r][col] = accV[ct][r] + bvv;
    }
    #pragma unroll
    for (int rr = 0; rr < 16; ++rr) {
        const int grow = row0 + rr;
        if (grow < N)
            *(float2*)&QV32[(size_t)grow * 256 + 128 + cl] = *(const float2*)&lds[wid][rr][cl];
    }
}

// ------------------------------------------------------------------
// KV projection via MFMA; interleaved bf16 row KV16[m][256]
// (K cols 0..127, V cols 128..255), coalesced packed stores.
// ------------------------------------------------------------------
__global__ __launch_bounds__(256) void proj_kv_mfma(
    const float* __restrict__ key, const float* __restrict__ value,
    const short* __restrict__ Wkp, const short* __restrict__ Wvp,
    const float* __restrict__ bk, const float* __restrict__ bv,
    short* __restrict__ KV16, int M)
{
    __shared__ float lds[4][16][130];
    const int wid = threadIdx.x >> 6, lane = threadIdx.x & 63;
    const int row0 = (blockIdx.x * 4 + wid) * 16;
    if (row0 >= M) return;
    const int lr = lane & 15, lg = lane >> 4;

    bf16x8 afK[4], afV[4];
    const int arow = row0 + lr;
    const bool rowok = arow < M;
    #pragma unroll
    for (int ks = 0; ks < 4; ++ks) {
        float tk[8] = {0.f,0.f,0.f,0.f,0.f,0.f,0.f,0.f};
        float tv[8] = {0.f,0.f,0.f,0.f,0.f,0.f,0.f,0.f};
        if (rowok) {
            *(float4*)&tk[0] = *(const float4*)&key[(size_t)arow * DIM + ks * 32 + lg * 8];
            *(float4*)&tk[4] = *(const float4*)&key[(size_t)arow * DIM + ks * 32 + lg * 8 + 4];
            *(float4*)&tv[0] = *(const float4*)&value[(size_t)arow * DIM + ks * 32 + lg * 8];
            *(float4*)&tv[4] = *(const float4*)&value[(size_t)arow * DIM + ks * 32 + lg * 8 + 4];
        }
        bf16x8 a, b;
        #pragma unroll
        for (int j = 0; j < 8; ++j) { a[j] = f2bf(tk[j]); b[j] = f2bf(tv[j]); }
        afK[ks] = a; afV[ks] = b;
    }

    f32x4 accK[8], accV[8];
    #pragma unroll
    for (int ct = 0; ct < 8; ++ct) { accK[ct] = (f32x4)0.f; accV[ct] = (f32x4)0.f; }

    #pragma unroll
    for (int ks = 0; ks < 4; ++ks) {
        #pragma unroll
        for (int ct = 0; ct < 8; ++ct) {
            const size_t bo = (size_t)((ks * 8 + ct) * 64 + lane) * 8;
            const bf16x8 bk_ = *(const bf16x8*)&Wkp[bo];
            const bf16x8 bv_ = *(const bf16x8*)&Wvp[bo];
            accK[ct] = __builtin_amdgcn_mfma_f32_16x16x32_bf16(afK[ks], bk_, accK[ct], 0, 0, 0);
            accV[ct] = __builtin_amdgcn_mfma_f32_16x16x32_bf16(afV[ks], bv_, accV[ct], 0, 0, 0);
        }
    }

    const int cl = lane * 2;
    // K pass
    #pragma unroll
    for (int ct = 0; ct < 8; ++ct) {
        const int col = ct * 16 + lr;
        const float bkv = bk[col];
        #pragma unroll
        for (int r = 0; r < 4; ++r)
            lds[wid][lg * 4 + r][col] = accK[ct][r] + bkv;
    }
    #pragma unroll
    for (int rr = 0; rr < 16; ++rr) {
        const int grow = row0 + rr;
        if (grow < M) {
            const float2 q = *(const float2*)&lds[wid][rr][cl];
            *(unsigned*)&KV16[(size_t)grow * 256 + cl] = cvt_pk_bf16(q.x, q.y);
        }
    }
    // V pass
    #pragma unroll
    for (int ct = 0; ct < 8; ++ct) {
        const int col = ct * 16 + lr;
        const float bvv = bv[col];
        #pragma unroll
        for (int r = 0; r < 4; ++r)
            lds[wid][lg * 4 + r][col] = accV[ct][r] + bvv;
    }
    #pragma unroll
    for (int rr = 0; rr < 16; ++rr) {
        const int grow = row0 + rr;
        if (grow < M) {
            const float2 q = *(const float2*)&lds[wid][rr][cl];
            *(unsigned*)&KV16[(size_t)grow * 256 + 128 + cl] = cvt_pk_bf16(q.x, q.y);
        }
    }
}

// ------------------------------------------------------------------
// CSR build
// ------------------------------------------------------------------
__global__ void hist_kernel(const int* __restrict__ qidx, int* __restrict__ counts, int E)
{
    for (int e = blockIdx.x * blockDim.x + threadIdx.x; e < E; e += gridDim.x * blockDim.x)
        atomicAdd(&counts[qidx[e]], 1);
}

__global__ __launch_bounds__(256) void scan1_kernel(const int* __restrict__ counts,
                                                    int* __restrict__ bsum, int N)
{
    __shared__ int sh[256];
    int i = blockIdx.x * 256 + threadIdx.x;
    sh[threadIdx.x] = (i < N) ? counts[i] : 0;
    __syncthreads();
    #pragma unroll
    for (int off = 128; off; off >>= 1) {
        if (threadIdx.x < off) sh[threadIdx.x] += sh[threadIdx.x + off];
        __syncthreads();
    }
    if (threadIdx.x == 0) bsum[blockIdx.x] = sh[0];
}

__global__ __launch_bounds__(256) void scan2_kernel(const int* __restrict__ bsum,
                                                    int* __restrict__ boff, int B)
{
    int t = threadIdx.x;
    if (B > 256) {
        if (t == 0) { int run = 0; for (int i = 0; i < B; ++i) { int v = bsum[i]; boff[i] = run; run += v; } }
        return;
    }
    __shared__ int sh[256];
    int v = (t < B) ? bsum[t] : 0;
    sh[t] = v;
    __syncthreads();
    for (int off = 1; off < 256; off <<= 1) {
        int x = (t >= off) ? sh[t - off] : 0;
        __syncthreads();
        sh[t] += x;
        __syncthreads();
    }
    if (t < B) boff[t] = sh[t] - v;
}

__global__ __launch_bounds__(256) void scan3_kernel(const int* __restrict__ counts,
                                                    const int* __restrict__ boff,
                                                    int* __restrict__ offsets,
                                                    int* __restrict__ cursor,
                                                    int N, int E)
{
    __shared__ int sh[256];
    int t = threadIdx.x;
    int i = blockIdx.x * 256 + t;
    int v = (i < N) ? counts[i] : 0;
    sh[t] = v;
    __syncthreads();
    for (int off = 1; off < 256; off <<= 1) {
        int x = (t >= off) ? sh[t - off] : 0;
        __syncthreads();
        sh[t] += x;
        __syncthreads();
    }
    int base = boff[blockIdx.x];
    if (i < N) {
        int o = base + sh[t] - v;
        offsets[i] = o;
        cursor[i] = o;
    }
    if (i == 0) offsets[N] = E;
}

__global__ void fill_kernel(const int* __restrict__ qidx, const int* __restrict__ kidx,
                            int* __restrict__ cursor, int* __restrict__ ksorted, int E)
{
    for (int e = blockIdx.x * blockDim.x + threadIdx.x; e < E; e += gridDim.x * blockDim.x) {
        int q = qidx[e];
        int pos = atomicAdd(&cursor[q], 1);
        ksorted[pos] = kidx[e];
    }
}

// ------------------------------------------------------------------
// Node-centric online-softmax aggregation, v4:
//  - a*prelu(x) = c1*x + c2*|x|  (abs = free VOP3 modifier): 3 ops/dim
//  - 4-edge unroll (8 gathers + 4 swizzle chains in flight)
//  - defer-max fast path (no rescale unless __any(d > 8))
//  - QV32/KV16 interleaved rows: one base address per table
// ------------------------------------------------------------------
__global__ __launch_bounds__(256) void edge_agg_kernel(
    const float* __restrict__ QV32, const float* __restrict__ attnqq,
    const short* __restrict__ KV16,
    const int* __restrict__ ksorted, const int* __restrict__ offsets,
    const float* __restrict__ avec, const float* __restrict__ alpha_p,
    short* __restrict__ msgn16, int N)
{
    const int wid = threadIdx.x >> 6;
    const int lane = threadIdx.x & 63;
    const int n = blockIdx.x * 4 + wid;
    if (n >= N) return;

    const float al = alpha_p[0];
    const int d0 = lane * 2;
    const int h = lane >> 3;

    const float2 qq = *(const float2*)&QV32[(size_t)n * 256 + d0];
    const float2 vq = *(const float2*)&QV32[(size_t)n * 256 + 128 + d0];
    const float2 av = *(const float2*)&avec[d0];
    const float c1x = av.x * (1.f + al) * 0.5f, c2x = av.x * (1.f - al) * 0.5f;
    const float c1y = av.y * (1.f + al) * 0.5f, c2y = av.y * (1.f - al) * 0.5f;

    float m = attnqq[(size_t)n * NH + h];
    float den = 1.f;
    float accx = vq.x, accy = vq.y;

    const int p0 = offsets[n], p1 = offsets[n + 1];

    #define SCORE(kk2, sout)                                                     \
        {                                                                        \
            const float x0 = qq.x + bflo(kk2);                                   \
            const float x1 = qq.y + bfhi(kk2);                                   \
            float s_ = fmaf(c1x, x0, fmaf(c2x, __builtin_fabsf(x0),              \
                       fmaf(c1y, x1, c2y * __builtin_fabsf(x1))));               \
            s_ += swz_xor1(s_);                                                  \
            s_ += swz_xor2(s_);                                                  \
            s_ += swz_xor4(s_);                                                  \
            sout = s_;                                                           \
        }
    #define SLOW(s_, vv_)                                                        \
        {                                                                        \
            const float nm = fmaxf(m, s_);                                       \
            const float c = __expf(m - nm);                                      \
            const float w = __expf(s_ - nm);                                     \
            den = den * c + w;                                                   \
            accx = fmaf(accx, c, w * bflo(vv_));                                 \
            accy = fmaf(accy, c, w * bfhi(vv_));                                 \
            m = nm;                                                              \
        }

    int p = p0;
    const int nrem = (p1 - p0) & 3;
    for (int i = 0; i < nrem; ++i, ++p) {
        const int ki = ksorted[p];
        const unsigned kk2 = *(const unsigned*)&KV16[(size_t)ki * 256 + d0];
        const unsigned vv2 = *(const unsigned*)&KV16[(size_t)ki * 256 + 128 + d0];
        float s;
        SCORE(kk2, s);
        const float d = s - m;
        if (__any(d > 8.f)) {
            SLOW(s, vv2);
        } else {
            const float w = __expf(d);
            den += w;
            accx = fmaf(w, bflo(vv2), accx);
            accy = fmaf(w, bfhi(vv2), accy);
        }
    }

    for (; p < p1; p += 4) {
        const int ka = ksorted[p],     kb = ksorted[p + 1];
        const int kc = ksorted[p + 2], kd = ksorted[p + 3];
        const unsigned kka = *(const unsigned*)&KV16[(size_t)ka * 256 + d0];
        const unsigned kkb = *(const unsigned*)&KV16[(size_t)kb * 256 + d0];
        const unsigned kkc = *(const unsigned*)&KV16[(size_t)kc * 256 + d0];
        const unsigned kkd = *(const unsigned*)&KV16[(size_t)kd * 256 + d0];
        const unsigned vva = *(const unsigned*)&KV16[(size_t)ka * 256 + 128 + d0];
        const unsigned vvb = *(const unsigned*)&KV16[(size_t)kb * 256 + 128 + d0];
        const unsigned vvc = *(const unsigned*)&KV16[(size_t)kc * 256 + 128 + d0];
        const unsigned vvd = *(const unsigned*)&KV16[(size_t)kd * 256 + 128 + d0];
        float sa, sb, sc, sd;
        SCORE(kka, sa);
        SCORE(kkb, sb);
        SCORE(kkc, sc);
        SCORE(kkd, sd);
        const float da = sa - m, db = sb - m, dc = sc - m, dd = sd - m;
        const float dmax = fmaxf(fmaxf(da, db), fmaxf(dc, dd));
        if (__any(dmax > 8.f)) {
            SLOW(sa, vva);
            SLOW(sb, vvb);
            SLOW(sc, vvc);
            SLOW(sd, vvd);
        } else {
            const float wa = __expf(da);
            const float wb = __expf(db);
            const float wc = __expf(dc);
            const float wd = __expf(dd);
            den += (wa + wb) + (wc + wd);
            accx = fmaf(wa, bflo(vva), fmaf(wb, bflo(vvb),
                   fmaf(wc, bflo(vvc), fmaf(wd, bflo(vvd), accx))));
            accy = fmaf(wa, bfhi(vva), fmaf(wb, bfhi(vvb),
                   fmaf(wc, bfhi(vvc), fmaf(wd, bfhi(vvd), accy))));
        }
    }
    #undef SCORE
    #undef SLOW

    const float inv = 1.f / den;
    *(unsigned*)&msgn16[(size_t)n * DIM + d0] = cvt_pk_bf16(accx * inv, accy * inv);
}

// ------------------------------------------------------------------
// Output projection (MFMA, bf16 A) + residual + LayerNorm.
// ------------------------------------------------------------------
__global__ __launch_bounds__(256) void out_ln_mfma(
    const short* __restrict__ msgn16, const short* __restrict__ Wpp,
    const float* __restrict__ bp, const float* __restrict__ query,
    const float* __restrict__ gamma, const float* __restrict__ beta,
    float* __restrict__ out, int N)
{
    __shared__ float ys[64][130];
    const int wid = threadIdx.x >> 6, lane = threadIdx.x & 63;
    const int rowbase = blockIdx.x * 64;
    const int row0 = rowbase + wid * 16;
    const int lr = lane & 15, lg = lane >> 4;

    if (row0 < N) {
        bf16x8 afrag[4];
        const int arow = row0 + lr;
        const bool rowok = arow < N;
        #pragma unroll
        for (int ks = 0; ks < 4; ++ks) {
            if (rowok)
                afrag[ks] = *(const bf16x8*)&msgn16[(size_t)arow * DIM + ks * 32 + lg * 8];
            else {
                bf16x8 z;
                #pragma unroll
                for (int j = 0; j < 8; ++j) z[j] = 0;
                afrag[ks] = z;
            }
        }
        f32x4 acc[8];
        #pragma unroll
        for (int ct = 0; ct < 8; ++ct) acc[ct] = (f32x4)0.f;
        #pragma unroll
        for (int ks = 0; ks < 4; ++ks) {
            #pragma unroll
            for (int ct = 0; ct < 8; ++ct) {
                const size_t bo = (size_t)((ks * 8 + ct) * 64 + lane) * 8;
                const bf16x8 b_ = *(const bf16x8*)&Wpp[bo];
                acc[ct] = __builtin_amdgcn_mfma_f32_16x16x32_bf16(afrag[ks], b_, acc[ct], 0, 0, 0);
            }
        }
        #pragma unroll
        for (int ct = 0; ct < 8; ++ct) {
            const int col = ct * 16 + lr;
            const float bpv = bp[col];
            #pragma unroll
            for (int r = 0; r < 4; ++r)
                ys[wid * 16 + lg * 4 + r][col] = acc[ct][r] + bpv;
        }
    }
    __syncthreads();

    for (int rr = 0; rr < 16; ++rr) {
        const int r = wid * 16 + rr;
        const int grow = rowbase + r;
        if (grow >= N) break;
        const float y1 = ys[r][lane], y2 = ys[r][lane + 64];
        const float q1 = query[(size_t)grow * DIM + lane];
        const float q2 = query[(size_t)grow * DIM + lane + 64];
        const float r1 = y1 + q1, r2 = y2 + q2;
        float s = r1 + r2;
        float ss = r1 * r1 + r2 * r2;
        #pragma unroll
        for (int off = 32; off; off >>= 1) {
            s += __shfl_xor(s, off);
            ss += __shfl_xor(ss, off);
        }
        const float mu = s * (1.f / DIM);
        const float var = ss * (1.f / DIM) - mu * mu;
        const float rstd = rsqrtf(var + LN_EPS);
        out[(size_t)grow * DIM + lane] = gamma[lane] * (r1 - mu) * rstd + beta[lane];
        out[(size_t)grow * DIM + lane + 64] = gamma[lane + 64] * (r2 - mu) * rstd + beta[lane + 64];
    }
}

// ------------------------------------------------------------------
extern "C" void kernel_launch(void* const* d_in, const int* in_sizes, int n_in,
                              void* d_out, int out_size, void* d_ws, size_t ws_size,
                              hipStream_t stream) {
    const float* query = (const float*)d_in[0];
    const float* key   = (const float*)d_in[1];
    const float* value = (const float*)d_in[2];
    const int* query_idx = (const int*)d_in[3];
    const int* key_idx   = (const int*)d_in[4];
    const float* Wq = (const float*)d_in[5];
    const float* bq = (const float*)d_in[6];
    const float* Wk = (const float*)d_in[7];
    const float* bk = (const float*)d_in[8];
    const float* Wv = (const float*)d_in[9];
    const float* bv = (const float*)d_in[10];
    const float* Wp = (const float*)d_in[11];
    const float* bp = (const float*)d_in[12];
    const float* avec  = (const float*)d_in[13];
    const float* alpha = (const float*)d_in[14];
    const float* gamma = (const float*)d_in[15];
    const float* beta  = (const float*)d_in[16];
    float* out = (float*)d_out;

    const int N = in_sizes[0] / DIM;
    const int M = in_sizes[1] / DIM;
    const int E = in_sizes[3];

    // workspace layout (all 16B aligned)
    float* f = (float*)d_ws;
    float* QV32 = f;    f += (size_t)N * 256;
    float* attnqq = f;  f += (size_t)N * NH;
    short* sp = (short*)f;
    short* KV16 = sp;   sp += (size_t)M * 256;
    short* msgn16 = sp; sp += (size_t)N * DIM;
    short* Wqp = sp;    sp += DIM * DIM;
    short* Wkp = sp;    sp += DIM * DIM;
    short* Wvp = sp;    sp += DIM * DIM;
    short* Wpp = sp;    sp += DIM * DIM;
    int* ip = (int*)(((size_t)sp + 15) & ~(size_t)15);
    int* counts  = ip;  ip += N;
    int* offsets = ip;  ip += N + 1;
    int* cursor  = ip;  ip += N;
    int* bsum    = ip;  ip += 4096;
    int* boff    = ip;  ip += 4096;
    int* ksorted = ip;  ip += E;

    const int B = (N + 255) / 256;

    hipMemsetAsync(counts, 0, (size_t)N * sizeof(int), stream);

    pack_w_kernel<<<32, 256, 0, stream>>>(Wq, Wk, Wv, Wp, Wqp, Wkp, Wvp, Wpp);

    proj_query_mfma<<<(N + 63) / 64, 256, 0, stream>>>(
        query, Wqp, Wkp, Wvp, bq, bk, bv, avec, alpha, QV32, attnqq, N);
    proj_kv_mfma<<<(M + 63) / 64, 256, 0, stream>>>(
        key, value, Wkp, Wvp, bk, bv, KV16, M);

    hist_kernel<<<1024, 256, 0, stream>>>(query_idx, counts, E);
    scan1_kernel<<<B, 256, 0, stream>>>(counts, bsum, N);
    scan2_kernel<<<1, 256, 0, stream>>>(bsum, boff, B);
    scan3_kernel<<<B, 256, 0, stream>>>(counts, boff, offsets, cursor, N, E);
    fill_kernel<<<1024, 256, 0, stream>>>(query_idx, key_idx, cursor, ksorted, E);

    edge_agg_kernel<<<(N + 3) / 4, 256, 0, stream>>>(
        QV32, attnqq, KV16, ksorted, offsets, avec, alpha, msgn16, N);

    out_ln_mfma<<<(N + 63) / 64, 256, 0, stream>>>(
        msgn16, Wpp, bp, query, gamma, beta, out, N);
}

// Round 5
// 224.378 us; speedup vs baseline: 1.9580x; 1.0178x over previous
//
#include <hip/hip_runtime.h>
#include <math.h>

#define DIM 128
#define NH 8
#define LN_EPS 1e-5f
#define NEGINF -3.0e38f

using bf16x8 = __attribute__((ext_vector_type(8))) short;
using f32x4  = __attribute__((ext_vector_type(4))) float;

__device__ __forceinline__ float prelu_f(float x, float al) { return x >= 0.f ? x : al * x; }

__device__ __forceinline__ short f2bf(float f) {
    unsigned u = __float_as_uint(f);
    unsigned r = (u + 0x7fffu + ((u >> 16) & 1u)) >> 16;
    return (short)r;
}
__device__ __forceinline__ float bflo(unsigned u) { return __uint_as_float(u << 16); }
__device__ __forceinline__ float bfhi(unsigned u) { return __uint_as_float(u & 0xffff0000u); }

__device__ __forceinline__ unsigned cvt_pk_bf16(float lo, float hi) {
    unsigned r;
    asm("v_cvt_pk_bf16_f32 %0, %1, %2" : "=v"(r) : "v"(lo), "v"(hi));
    return r;
}

// ds_swizzle xor within 32-lane halves (BitMode)
__device__ __forceinline__ float swz_xor1(float x) {
    return __int_as_float(__builtin_amdgcn_ds_swizzle(__float_as_int(x), 0x041F));
}
__device__ __forceinline__ float swz_xor2(float x) {
    return __int_as_float(__builtin_amdgcn_ds_swizzle(__float_as_int(x), 0x081F));
}
__device__ __forceinline__ float swz_xor4(float x) {
    return __int_as_float(__builtin_amdgcn_ds_swizzle(__float_as_int(x), 0x101F));
}
__device__ __forceinline__ float swz_xor8(float x) {
    return __int_as_float(__builtin_amdgcn_ds_swizzle(__float_as_int(x), 0x201F));
}
__device__ __forceinline__ float swz_xor16(float x) {
    return __int_as_float(__builtin_amdgcn_ds_swizzle(__float_as_int(x), 0x401F));
}
__device__ __forceinline__ float swz_xor32(float x) {
    return __shfl_xor(x, 32);
}

// ------------------------------------------------------------------
// Setup: pack 4 weight matrices into MFMA B-frag bf16 order (blocks 0..31)
// + histogram of query_idx (blocks 32..1055).
// ------------------------------------------------------------------
__global__ __launch_bounds__(256) void setup_kernel(
    const float* __restrict__ W0, const float* __restrict__ W1,
    const float* __restrict__ W2, const float* __restrict__ W3,
    short* __restrict__ P0, short* __restrict__ P1,
    short* __restrict__ P2, short* __restrict__ P3,
    const int* __restrict__ qidx, int* __restrict__ counts, int E)
{
    if (blockIdx.x < 32) {
        const int id = blockIdx.x * 256 + threadIdx.x;   // 8192 total
        const int mat = id >> 11;
        const int rem = id & 2047;
        const int ks = rem >> 9;
        const int ct = (rem >> 6) & 7;
        const int lane = rem & 63;
        const int lr = lane & 15, lg = lane >> 4;
        const float* W = mat == 0 ? W0 : mat == 1 ? W1 : mat == 2 ? W2 : W3;
        short* P = mat == 0 ? P0 : mat == 1 ? P1 : mat == 2 ? P2 : P3;
        short v[8];
        #pragma unroll
        for (int r = 0; r < 8; ++r)
            v[r] = f2bf(W[(ks * 32 + lg * 8 + r) * DIM + ct * 16 + lr]);
        *(bf16x8*)&P[(size_t)((ks * 8 + ct) * 64 + lane) * 8] = *(bf16x8*)v;
    } else {
        const int b = blockIdx.x - 32;
        for (int e = b * 256 + threadIdx.x; e < E; e += 1024 * 256)
            atomicAdd(&counts[qidx[e]], 1);
    }
}

// ------------------------------------------------------------------
// Fused projections. Blocks [0, nb): query rows -> QV16 (bf16 Q|Vq),
// attnqq. Blocks [nb, nb+mb): key/value rows -> KV16 (bf16 K|Vv).
// ------------------------------------------------------------------
__global__ __launch_bounds__(256) void proj_all_mfma(
    const float* __restrict__ query,
    const float* __restrict__ key, const float* __restrict__ value,
    const short* __restrict__ Wqp, const short* __restrict__ Wkp, const short* __restrict__ Wvp,
    const float* __restrict__ bq, const float* __restrict__ bk, const float* __restrict__ bv,
    const float* __restrict__ avec, const float* __restrict__ alpha_p,
    short* __restrict__ QV16, float* __restrict__ attnqq,
    short* __restrict__ KV16, int N, int M, int nb)
{
    __shared__ float lds[4][16][130];
    const int wid = threadIdx.x >> 6, lane = threadIdx.x & 63;
    const int lr = lane & 15, lg = lane >> 4;
    const int cl = lane * 2;

    if ((int)blockIdx.x < nb) {
        const int row0 = (blockIdx.x * 4 + wid) * 16;
        if (row0 >= N) return;
        bf16x8 afrag[4];
        const int arow = row0 + lr;
        const bool rowok = arow < N;
        #pragma unroll
        for (int ks = 0; ks < 4; ++ks) {
            float t[8] = {0.f,0.f,0.f,0.f,0.f,0.f,0.f,0.f};
            if (rowok) {
                *(float4*)&t[0] = *(const float4*)&query[(size_t)arow * DIM + ks * 32 + lg * 8];
                *(float4*)&t[4] = *(const float4*)&query[(size_t)arow * DIM + ks * 32 + lg * 8 + 4];
            }
            bf16x8 a;
            #pragma unroll
            for (int j = 0; j < 8; ++j) a[j] = f2bf(t[j]);
            afrag[ks] = a;
        }

        f32x4 accQ[8], accK[8], accV[8];
        #pragma unroll
        for (int ct = 0; ct < 8; ++ct) { accQ[ct] = (f32x4)0.f; accK[ct] = (f32x4)0.f; accV[ct] = (f32x4)0.f; }
        #pragma unroll
        for (int ks = 0; ks < 4; ++ks) {
            #pragma unroll
            for (int ct = 0; ct < 8; ++ct) {
                const size_t bo = (size_t)((ks * 8 + ct) * 64 + lane) * 8;
                const bf16x8 bq_ = *(const bf16x8*)&Wqp[bo];
                const bf16x8 bk_ = *(const bf16x8*)&Wkp[bo];
                const bf16x8 bv_ = *(const bf16x8*)&Wvp[bo];
                accQ[ct] = __builtin_amdgcn_mfma_f32_16x16x32_bf16(afrag[ks], bq_, accQ[ct], 0, 0, 0);
                accK[ct] = __builtin_amdgcn_mfma_f32_16x16x32_bf16(afrag[ks], bk_, accK[ct], 0, 0, 0);
                accV[ct] = __builtin_amdgcn_mfma_f32_16x16x32_bf16(afrag[ks], bv_, accV[ct], 0, 0, 0);
            }
        }

        const float al = alpha_p[0];
        // attnqq + stage Q
        #pragma unroll
        for (int ct = 0; ct < 8; ++ct) {
            const int col = ct * 16 + lr;
            const float bqv = bq[col], bkv = bk[col], av = avec[col];
            #pragma unroll
            for (int r = 0; r < 4; ++r) {
                const int grow = row0 + lg * 4 + r;
                const float qv = accQ[ct][r] + bqv;
                const float kv = accK[ct][r] + bkv;
                lds[wid][lg * 4 + r][col] = qv;
                float part = av * prelu_f(qv + kv, al);
                part += swz_xor1(part);
                part += swz_xor2(part);
                part += swz_xor4(part);
                part += swz_xor8(part);
                if (lr == 0 && grow < N) attnqq[(size_t)grow * NH + ct] = part;
            }
        }
        #pragma unroll
        for (int rr = 0; rr < 16; ++rr) {
            const int grow = row0 + rr;
            if (grow < N) {
                const float2 t = *(const float2*)&lds[wid][rr][cl];
                *(unsigned*)&QV16[(size_t)grow * 256 + cl] = cvt_pk_bf16(t.x, t.y);
            }
        }
        // stage Vq
        #pragma unroll
        for (int ct = 0; ct < 8; ++ct) {
            const int col = ct * 16 + lr;
            const float bvv = bv[col];
            #pragma unroll
            for (int r = 0; r < 4; ++r)
                lds[wid][lg * 4 + r][col] = accV[ct][r] + bvv;
        }
        #pragma unroll
        for (int rr = 0; rr < 16; ++rr) {
            const int grow = row0 + rr;
            if (grow < N) {
                const float2 t = *(const float2*)&lds[wid][rr][cl];
                *(unsigned*)&QV16[(size_t)grow * 256 + 128 + cl] = cvt_pk_bf16(t.x, t.y);
            }
        }
    } else {
        const int row0 = (((int)blockIdx.x - nb) * 4 + wid) * 16;
        if (row0 >= M) return;
        bf16x8 afK[4], afV[4];
        const int arow = row0 + lr;
        const bool rowok = arow < M;
        #pragma unroll
        for (int ks = 0; ks < 4; ++ks) {
            float tk[8] = {0.f,0.f,0.f,0.f,0.f,0.f,0.f,0.f};
            float tv[8] = {0.f,0.f,0.f,0.f,0.f,0.f,0.f,0.f};
            if (rowok) {
                *(float4*)&tk[0] = *(const float4*)&key[(size_t)arow * DIM + ks * 32 + lg * 8];
                *(float4*)&tk[4] = *(const float4*)&key[(size_t)arow * DIM + ks * 32 + lg * 8 + 4];
                *(float4*)&tv[0] = *(const float4*)&value[(size_t)arow * DIM + ks * 32 + lg * 8];
                *(float4*)&tv[4] = *(const float4*)&value[(size_t)arow * DIM + ks * 32 + lg * 8 + 4];
            }
            bf16x8 a, b;
            #pragma unroll
            for (int j = 0; j < 8; ++j) { a[j] = f2bf(tk[j]); b[j] = f2bf(tv[j]); }
            afK[ks] = a; afV[ks] = b;
        }

        f32x4 accK[8], accV[8];
        #pragma unroll
        for (int ct = 0; ct < 8; ++ct) { accK[ct] = (f32x4)0.f; accV[ct] = (f32x4)0.f; }
        #pragma unroll
        for (int ks = 0; ks < 4; ++ks) {
            #pragma unroll
            for (int ct = 0; ct < 8; ++ct) {
                const size_t bo = (size_t)((ks * 8 + ct) * 64 + lane) * 8;
                const bf16x8 bk_ = *(const bf16x8*)&Wkp[bo];
                const bf16x8 bv_ = *(const bf16x8*)&Wvp[bo];
                accK[ct] = __builtin_amdgcn_mfma_f32_16x16x32_bf16(afK[ks], bk_, accK[ct], 0, 0, 0);
                accV[ct] = __builtin_amdgcn_mfma_f32_16x16x32_bf16(afV[ks], bv_, accV[ct], 0, 0, 0);
            }
        }

        // K pass
        #pragma unroll
        for (int ct = 0; ct < 8; ++ct) {
            const int col = ct * 16 + lr;
            const float bkv = bk[col];
            #pragma unroll
            for (int r = 0; r < 4; ++r)
                lds[wid][lg * 4 + r][col] = accK[ct][r] + bkv;
        }
        #pragma unroll
        for (int rr = 0; rr < 16; ++rr) {
            const int grow = row0 + rr;
            if (grow < M) {
                const float2 t = *(const float2*)&lds[wid][rr][cl];
                *(unsigned*)&KV16[(size_t)grow * 256 + cl] = cvt_pk_bf16(t.x, t.y);
            }
        }
        // V pass
        #pragma unroll
        for (int ct = 0; ct < 8; ++ct) {
            const int col = ct * 16 + lr;
            const float bvv = bv[col];
            #pragma unroll
            for (int r = 0; r < 4; ++r)
                lds[wid][lg * 4 + r][col] = accV[ct][r] + bvv;
        }
        #pragma unroll
        for (int rr = 0; rr < 16; ++rr) {
            const int grow = row0 + rr;
            if (grow < M) {
                const float2 t = *(const float2*)&lds[wid][rr][cl];
                *(unsigned*)&KV16[(size_t)grow * 256 + 128 + cl] = cvt_pk_bf16(t.x, t.y);
            }
        }
    }
}

// ------------------------------------------------------------------
// CSR scan chain
// ------------------------------------------------------------------
__global__ __launch_bounds__(256) void scan1_kernel(const int* __restrict__ counts,
                                                    int* __restrict__ bsum, int N)
{
    __shared__ int sh[256];
    int i = blockIdx.x * 256 + threadIdx.x;
    sh[threadIdx.x] = (i < N) ? counts[i] : 0;
    __syncthreads();
    #pragma unroll
    for (int off = 128; off; off >>= 1) {
        if (threadIdx.x < off) sh[threadIdx.x] += sh[threadIdx.x + off];
        __syncthreads();
    }
    if (threadIdx.x == 0) bsum[blockIdx.x] = sh[0];
}

__global__ __launch_bounds__(256) void scan2_kernel(const int* __restrict__ bsum,
                                                    int* __restrict__ boff, int B)
{
    int t = threadIdx.x;
    if (B > 256) {
        if (t == 0) { int run = 0; for (int i = 0; i < B; ++i) { int v = bsum[i]; boff[i] = run; run += v; } }
        return;
    }
    __shared__ int sh[256];
    int v = (t < B) ? bsum[t] : 0;
    sh[t] = v;
    __syncthreads();
    for (int off = 1; off < 256; off <<= 1) {
        int x = (t >= off) ? sh[t - off] : 0;
        __syncthreads();
        sh[t] += x;
        __syncthreads();
    }
    if (t < B) boff[t] = sh[t] - v;
}

__global__ __launch_bounds__(256) void scan3_kernel(const int* __restrict__ counts,
                                                    const int* __restrict__ boff,
                                                    int* __restrict__ offsets,
                                                    int* __restrict__ cursor,
                                                    int N, int E)
{
    __shared__ int sh[256];
    int t = threadIdx.x;
    int i = blockIdx.x * 256 + t;
    int v = (i < N) ? counts[i] : 0;
    sh[t] = v;
    __syncthreads();
    for (int off = 1; off < 256; off <<= 1) {
        int x = (t >= off) ? sh[t - off] : 0;
        __syncthreads();
        sh[t] += x;
        __syncthreads();
    }
    int base = boff[blockIdx.x];
    if (i < N) {
        int o = base + sh[t] - v;
        offsets[i] = o;
        cursor[i] = o;
    }
    if (i == 0) offsets[N] = E;
}

__global__ void fill_kernel(const int* __restrict__ qidx, const int* __restrict__ kidx,
                            int* __restrict__ cursor, int* __restrict__ ksorted, int E)
{
    for (int e = blockIdx.x * blockDim.x + threadIdx.x; e < E; e += gridDim.x * blockDim.x) {
        int q = qidx[e];
        int pos = atomicAdd(&cursor[q], 1);
        ksorted[pos] = kidx[e];
    }
}

// ------------------------------------------------------------------
// Edge aggregation v5: lane = (edge_slot e = lane>>3, head h = lane&7).
// Each lane scores one edge x one head fully in-lane (16 dims), keeps a
// per-lane online-softmax partial with shared-m fast path, merged across
// the 8 edge slots at the end (cheap sum if m never diverged).
// K/V rows still read fully-coalesced: 8 h-lanes cover one 256B row,
// 8 rows per load instruction.
// ------------------------------------------------------------------
__global__ __launch_bounds__(256) void edge_agg_kernel(
    const short* __restrict__ QV16, const float* __restrict__ attnqq,
    const short* __restrict__ KV16,
    const int* __restrict__ ksorted, const int* __restrict__ offsets,
    const float* __restrict__ avec, const float* __restrict__ alpha_p,
    short* __restrict__ msgn16, int N)
{
    const int wid = threadIdx.x >> 6;
    const int lane = threadIdx.x & 63;
    const int n = blockIdx.x * 4 + wid;
    if (n >= N) return;

    const int h = lane & 7;      // head
    const int e = lane >> 3;     // edge slot
    const float al = alpha_p[0];

    // per-head score coefficients: a*prelu(x) = c1*x + c2*|x|
    float c1[16], c2[16];
    {
        const float s1 = (1.f + al) * 0.5f, s2 = (1.f - al) * 0.5f;
        #pragma unroll
        for (int j = 0; j < 4; ++j) {
            const float4 a4 = *(const float4*)&avec[h * 16 + j * 4];
            c1[j*4+0] = a4.x * s1; c2[j*4+0] = a4.x * s2;
            c1[j*4+1] = a4.y * s1; c2[j*4+1] = a4.y * s2;
            c1[j*4+2] = a4.z * s1; c2[j*4+2] = a4.z * s2;
            c1[j*4+3] = a4.w * s1; c2[j*4+3] = a4.w * s2;
        }
    }

    // Q segment for this head (16 bf16)
    const size_t qb = (size_t)n * 256 + h * 16;
    float q[16];
    {
        const uint4 lo = *(const uint4*)&QV16[qb];
        const uint4 hi = *(const uint4*)&QV16[qb + 8];
        const unsigned qd[8] = {lo.x, lo.y, lo.z, lo.w, hi.x, hi.y, hi.z, hi.w};
        #pragma unroll
        for (int j = 0; j < 8; ++j) { q[2*j] = bflo(qd[j]); q[2*j+1] = bfhi(qd[j]); }
    }

    float acc[16];
    float den;
    if (e == 0) {
        const uint4 lo = *(const uint4*)&QV16[qb + 128];
        const uint4 hi = *(const uint4*)&QV16[qb + 136];
        const unsigned vd[8] = {lo.x, lo.y, lo.z, lo.w, hi.x, hi.y, hi.z, hi.w};
        #pragma unroll
        for (int j = 0; j < 8; ++j) { acc[2*j] = bflo(vd[j]); acc[2*j+1] = bfhi(vd[j]); }
        den = 1.f;
    } else {
        #pragma unroll
        for (int d = 0; d < 16; ++d) acc[d] = 0.f;
        den = 0.f;
    }

    float m = attnqq[(size_t)n * NH + h];
    const int p0 = offsets[n], p1 = offsets[n + 1];
    bool div = false;

    int idx = p0 + e;
    bool valid = idx < p1;
    int ki = valid ? ksorted[idx] : 0;

    for (int base = p0; base < p1; base += 8) {
        const int cki = ki;
        const bool cval = valid;
        const int nidx = base + 8 + e;
        valid = nidx < p1;
        ki = valid ? ksorted[nidx] : 0;

        const size_t kb = (size_t)cki * 256 + h * 16;
        const uint4 klo = *(const uint4*)&KV16[kb];
        const uint4 khi = *(const uint4*)&KV16[kb + 8];
        const uint4 vlo = *(const uint4*)&KV16[kb + 128];
        const uint4 vhi = *(const uint4*)&KV16[kb + 136];
        const unsigned kd[8] = {klo.x, klo.y, klo.z, klo.w, khi.x, khi.y, khi.z, khi.w};
        const unsigned vd[8] = {vlo.x, vlo.y, vlo.z, vlo.w, vhi.x, vhi.y, vhi.z, vhi.w};

        float sA = 0.f, sB = 0.f;
        #pragma unroll
        for (int j = 0; j < 8; ++j) {
            const float x0 = q[2*j]   + bflo(kd[j]);
            const float x1 = q[2*j+1] + bfhi(kd[j]);
            sA = fmaf(c1[2*j],   x0, fmaf(c2[2*j],   __builtin_fabsf(x0), sA));
            sB = fmaf(c1[2*j+1], x1, fmaf(c2[2*j+1], __builtin_fabsf(x1), sB));
        }
        const float s = cval ? (sA + sB) : NEGINF;
        const float d_ = s - m;

        if (__any(d_ > 8.f)) {
            div = true;
            const float nm = fmaxf(m, s);
            const float c = __expf(m - nm);
            const float w = __expf(s - nm);
            den = den * c + w;
            #pragma unroll
            for (int j = 0; j < 8; ++j) {
                acc[2*j]   = fmaf(acc[2*j],   c, w * bflo(vd[j]));
                acc[2*j+1] = fmaf(acc[2*j+1], c, w * bfhi(vd[j]));
            }
            m = nm;
        } else {
            const float w = __expf(d_);   // 0 for invalid lanes
            den += w;
            #pragma unroll
            for (int j = 0; j < 8; ++j) {
                acc[2*j]   = fmaf(w, bflo(vd[j]), acc[2*j]);
                acc[2*j+1] = fmaf(w, bfhi(vd[j]), acc[2*j+1]);
            }
        }
    }

    // merge across the 8 edge slots (lane bits 3,4,5)
    #define MERGE_ROUND(SWZ)                                    \
        {                                                       \
            const float m2 = SWZ(m);                            \
            const float den2 = SWZ(den);                        \
            const float nm = fmaxf(m, m2);                      \
            const float ca = __expf(m - nm);                    \
            const float cb = __expf(m2 - nm);                   \
            den = den * ca + den2 * cb;                         \
            _Pragma("unroll")                                   \
            for (int d = 0; d < 16; ++d)                        \
                acc[d] = acc[d] * ca + SWZ(acc[d]) * cb;        \
            m = nm;                                             \
        }
    #define SUM_ROUND(SWZ)                                      \
        {                                                       \
            den += SWZ(den);                                    \
            _Pragma("unroll")                                   \
            for (int d = 0; d < 16; ++d) acc[d] += SWZ(acc[d]); \
        }

    if (div) {
        MERGE_ROUND(swz_xor8);
        MERGE_ROUND(swz_xor16);
        MERGE_ROUND(swz_xor32);
    } else {
        SUM_ROUND(swz_xor8);
        SUM_ROUND(swz_xor16);
        SUM_ROUND(swz_xor32);
    }
    #undef MERGE_ROUND
    #undef SUM_ROUND

    if (e == 0) {
        const float inv = 1.f / den;
        unsigned u[8];
        #pragma unroll
        for (int j = 0; j < 8; ++j)
            u[j] = cvt_pk_bf16(acc[2*j] * inv, acc[2*j+1] * inv);
        *(uint4*)&msgn16[(size_t)n * DIM + h * 16]     = make_uint4(u[0], u[1], u[2], u[3]);
        *(uint4*)&msgn16[(size_t)n * DIM + h * 16 + 8] = make_uint4(u[4], u[5], u[6], u[7]);
    }
}

// ------------------------------------------------------------------
// Output projection (MFMA) + residual + LayerNorm.
// ------------------------------------------------------------------
__global__ __launch_bounds__(256) void out_ln_mfma(
    const short* __restrict__ msgn16, const short* __restrict__ Wpp,
    const float* __restrict__ bp, const float* __restrict__ query,
    const float* __restrict__ gamma, const float* __restrict__ beta,
    float* __restrict__ out, int N)
{
    __shared__ float ys[64][130];
    const int wid = threadIdx.x >> 6, lane = threadIdx.x & 63;
    const int rowbase = blockIdx.x * 64;
    const int row0 = rowbase + wid * 16;
    const int lr = lane & 15, lg = lane >> 4;

    if (row0 < N) {
        bf16x8 afrag[4];
        const int arow = row0 + lr;
        const bool rowok = arow < N;
        #pragma unroll
        for (int ks = 0; ks < 4; ++ks) {
            if (rowok)
                afrag[ks] = *(const bf16x8*)&msgn16[(size_t)arow * DIM + ks * 32 + lg * 8];
            else {
                bf16x8 z;
                #pragma unroll
                for (int j = 0; j < 8; ++j) z[j] = 0;
                afrag[ks] = z;
            }
        }
        f32x4 acc[8];
        #pragma unroll
        for (int ct = 0; ct < 8; ++ct) acc[ct] = (f32x4)0.f;
        #pragma unroll
        for (int ks = 0; ks < 4; ++ks) {
            #pragma unroll
            for (int ct = 0; ct < 8; ++ct) {
                const size_t bo = (size_t)((ks * 8 + ct) * 64 + lane) * 8;
                const bf16x8 b_ = *(const bf16x8*)&Wpp[bo];
                acc[ct] = __builtin_amdgcn_mfma_f32_16x16x32_bf16(afrag[ks], b_, acc[ct], 0, 0, 0);
            }
        }
        #pragma unroll
        for (int ct = 0; ct < 8; ++ct) {
            const int col = ct * 16 + lr;
            const float bpv = bp[col];
            #pragma unroll
            for (int r = 0; r < 4; ++r)
                ys[wid * 16 + lg * 4 + r][col] = acc[ct][r] + bpv;
        }
    }
    __syncthreads();

    for (int rr = 0; rr < 16; ++rr) {
        const int r = wid * 16 + rr;
        const int grow = rowbase + r;
        if (grow >= N) break;
        const float y1 = ys[r][lane], y2 = ys[r][lane + 64];
        const float q1 = query[(size_t)grow * DIM + lane];
        const float q2 = query[(size_t)grow * DIM + lane + 64];
        const float r1 = y1 + q1, r2 = y2 + q2;
        float s = r1 + r2;
        float ss = r1 * r1 + r2 * r2;
        #pragma unroll
        for (int off = 32; off; off >>= 1) {
            s += __shfl_xor(s, off);
            ss += __shfl_xor(ss, off);
        }
        const float mu = s * (1.f / DIM);
        const float var = ss * (1.f / DIM) - mu * mu;
        const float rstd = rsqrtf(var + LN_EPS);
        out[(size_t)grow * DIM + lane] = gamma[lane] * (r1 - mu) * rstd + beta[lane];
        out[(size_t)grow * DIM + lane + 64] = gamma[lane + 64] * (r2 - mu) * rstd + beta[lane + 64];
    }
}

// ------------------------------------------------------------------
extern "C" void kernel_launch(void* const* d_in, const int* in_sizes, int n_in,
                              void* d_out, int out_size, void* d_ws, size_t ws_size,
                              hipStream_t stream) {
    const float* query = (const float*)d_in[0];
    const float* key   = (const float*)d_in[1];
    const float* value = (const float*)d_in[2];
    const int* query_idx = (const int*)d_in[3];
    const int* key_idx   = (const int*)d_in[4];
    const float* Wq = (const float*)d_in[5];
    const float* bq = (const float*)d_in[6];
    const float* Wk = (const float*)d_in[7];
    const float* bk = (const float*)d_in[8];
    const float* Wv = (const float*)d_in[9];
    const float* bv = (const float*)d_in[10];
    const float* Wp = (const float*)d_in[11];
    const float* bp = (const float*)d_in[12];
    const float* avec  = (const float*)d_in[13];
    const float* alpha = (const float*)d_in[14];
    const float* gamma = (const float*)d_in[15];
    const float* beta  = (const float*)d_in[16];
    float* out = (float*)d_out;

    const int N = in_sizes[0] / DIM;
    const int M = in_sizes[1] / DIM;
    const int E = in_sizes[3];

    // workspace layout (16B aligned)
    float* f = (float*)d_ws;
    float* attnqq = f;  f += (size_t)N * NH;
    short* sp = (short*)f;
    short* QV16 = sp;   sp += (size_t)N * 256;
    short* KV16 = sp;   sp += (size_t)M * 256;
    short* msgn16 = sp; sp += (size_t)N * DIM;
    short* Wqp = sp;    sp += DIM * DIM;
    short* Wkp = sp;    sp += DIM * DIM;
    short* Wvp = sp;    sp += DIM * DIM;
    short* Wpp = sp;    sp += DIM * DIM;
    int* ip = (int*)(((size_t)sp + 15) & ~(size_t)15);
    int* counts  = ip;  ip += N;
    int* offsets = ip;  ip += N + 1;
    int* cursor  = ip;  ip += N;
    int* bsum    = ip;  ip += 4096;
    int* boff    = ip;  ip += 4096;
    int* ksorted = ip;  ip += E;

    const int B = (N + 255) / 256;
    const int nb = (N + 63) / 64;
    const int mb = (M + 63) / 64;

    hipMemsetAsync(counts, 0, (size_t)N * sizeof(int), stream);

    setup_kernel<<<1056, 256, 0, stream>>>(Wq, Wk, Wv, Wp, Wqp, Wkp, Wvp, Wpp,
                                           query_idx, counts, E);

    scan1_kernel<<<B, 256, 0, stream>>>(counts, bsum, N);
    scan2_kernel<<<1, 256, 0, stream>>>(bsum, boff, B);
    scan3_kernel<<<B, 256, 0, stream>>>(counts, boff, offsets, cursor, N, E);
    fill_kernel<<<1024, 256, 0, stream>>>(query_idx, key_idx, cursor, ksorted, E);

    proj_all_mfma<<<nb + mb, 256, 0, stream>>>(
        query, key, value, Wqp, Wkp, Wvp, bq, bk, bv, avec, alpha,
        QV16, attnqq, KV16, N, M, nb);

    edge_agg_kernel<<<(N + 3) / 4, 256, 0, stream>>>(
        QV16, attnqq, KV16, ksorted, offsets, avec, alpha, msgn16, N);

    out_ln_mfma<<<(N + 63) / 64, 256, 0, stream>>>(
        msgn16, Wpp, bp, query, gamma, beta, out, N);
}

// Round 6
// 206.656 us; speedup vs baseline: 2.1259x; 1.0858x over previous
//
#include <hip/hip_runtime.h>
#include <math.h>

#define DIM 128
#define NH 8
#define LN_EPS 1e-5f
#define NEGINF -3.0e38f

using bf16x8 = __attribute__((ext_vector_type(8))) short;
using f32x4  = __attribute__((ext_vector_type(4))) float;

__device__ __forceinline__ float prelu_f(float x, float al) { return x >= 0.f ? x : al * x; }

__device__ __forceinline__ short f2bf(float f) {
    unsigned u = __float_as_uint(f);
    unsigned r = (u + 0x7fffu + ((u >> 16) & 1u)) >> 16;
    return (short)r;
}
__device__ __forceinline__ float bflo(unsigned u) { return __uint_as_float(u << 16); }
__device__ __forceinline__ float bfhi(unsigned u) { return __uint_as_float(u & 0xffff0000u); }

__device__ __forceinline__ unsigned cvt_pk_bf16(float lo, float hi) {
    unsigned r;
    asm("v_cvt_pk_bf16_f32 %0, %1, %2" : "=v"(r) : "v"(lo), "v"(hi));
    return r;
}

// ds_swizzle xor within 32-lane halves (BitMode)
__device__ __forceinline__ float swz_xor1(float x) {
    return __int_as_float(__builtin_amdgcn_ds_swizzle(__float_as_int(x), 0x041F));
}
__device__ __forceinline__ float swz_xor2(float x) {
    return __int_as_float(__builtin_amdgcn_ds_swizzle(__float_as_int(x), 0x081F));
}
__device__ __forceinline__ float swz_xor4(float x) {
    return __int_as_float(__builtin_amdgcn_ds_swizzle(__float_as_int(x), 0x101F));
}
__device__ __forceinline__ float swz_xor8(float x) {
    return __int_as_float(__builtin_amdgcn_ds_swizzle(__float_as_int(x), 0x201F));
}
__device__ __forceinline__ float swz_xor16(float x) {
    return __int_as_float(__builtin_amdgcn_ds_swizzle(__float_as_int(x), 0x401F));
}
__device__ __forceinline__ float swz_xor32(float x) {
    return __shfl_xor(x, 32);
}

// ------------------------------------------------------------------
// Setup: pack 4 weight matrices into MFMA B-frag bf16 order (blocks 0..31)
// + histogram of query_idx (blocks 32..1055).
// ------------------------------------------------------------------
__global__ __launch_bounds__(256) void setup_kernel(
    const float* __restrict__ W0, const float* __restrict__ W1,
    const float* __restrict__ W2, const float* __restrict__ W3,
    short* __restrict__ P0, short* __restrict__ P1,
    short* __restrict__ P2, short* __restrict__ P3,
    const int* __restrict__ qidx, int* __restrict__ counts, int E)
{
    if (blockIdx.x < 32) {
        const int id = blockIdx.x * 256 + threadIdx.x;   // 8192 total
        const int mat = id >> 11;
        const int rem = id & 2047;
        const int ks = rem >> 9;
        const int ct = (rem >> 6) & 7;
        const int lane = rem & 63;
        const int lr = lane & 15, lg = lane >> 4;
        const float* W = mat == 0 ? W0 : mat == 1 ? W1 : mat == 2 ? W2 : W3;
        short* P = mat == 0 ? P0 : mat == 1 ? P1 : mat == 2 ? P2 : P3;
        short v[8];
        #pragma unroll
        for (int r = 0; r < 8; ++r)
            v[r] = f2bf(W[(ks * 32 + lg * 8 + r) * DIM + ct * 16 + lr]);
        *(bf16x8*)&P[(size_t)((ks * 8 + ct) * 64 + lane) * 8] = *(bf16x8*)v;
    } else {
        const int b = blockIdx.x - 32;
        for (int e = b * 256 + threadIdx.x; e < E; e += 1024 * 256)
            atomicAdd(&counts[qidx[e]], 1);
    }
}

// ------------------------------------------------------------------
// Fused projections v2 — occupancy-oriented:
//  - per-ct accumulators (#pragma unroll 1) keep <=8 acc regs live
//  - LDS stages cvt_pk-packed u32 rows (16.9KB, conflict-free writes)
//  - two passes per branch (Q|K then V), coalesced u32 row stores
// Blocks [0,nb): query -> QV16 (bf16 Q|Vq) + attnqq.
// Blocks [nb,nb+mb): key/value -> KV16 (bf16 K|Vv).
// ------------------------------------------------------------------
__global__ __launch_bounds__(256) void proj_all_mfma(
    const float* __restrict__ query,
    const float* __restrict__ key, const float* __restrict__ value,
    const short* __restrict__ Wqp, const short* __restrict__ Wkp, const short* __restrict__ Wvp,
    const float* __restrict__ bq, const float* __restrict__ bk, const float* __restrict__ bv,
    const float* __restrict__ avec, const float* __restrict__ alpha_p,
    short* __restrict__ QV16, float* __restrict__ attnqq,
    short* __restrict__ KV16, int N, int M, int nb)
{
    __shared__ unsigned lds[4][16][66];
    const int wid = threadIdx.x >> 6, lane = threadIdx.x & 63;
    const int lr = lane & 15, lg = lane >> 4;
    const bool evenlane = (lane & 1) == 0;

    if ((int)blockIdx.x < nb) {
        const int row0 = ((int)blockIdx.x * 4 + wid) * 16;
        if (row0 >= N) return;
        const int arow = row0 + lr;
        const bool rowok = arow < N;

        bf16x8 afrag[4];
        #pragma unroll
        for (int ks = 0; ks < 4; ++ks) {
            float t[8] = {0.f,0.f,0.f,0.f,0.f,0.f,0.f,0.f};
            if (rowok) {
                *(float4*)&t[0] = *(const float4*)&query[(size_t)arow * DIM + ks * 32 + lg * 8];
                *(float4*)&t[4] = *(const float4*)&query[(size_t)arow * DIM + ks * 32 + lg * 8 + 4];
            }
            union { bf16x8 v; unsigned u[4]; } a;
            a.u[0] = cvt_pk_bf16(t[0], t[1]);
            a.u[1] = cvt_pk_bf16(t[2], t[3]);
            a.u[2] = cvt_pk_bf16(t[4], t[5]);
            a.u[3] = cvt_pk_bf16(t[6], t[7]);
            afrag[ks] = a.v;
        }
        const float al = alpha_p[0];
        unsigned* qvout = (unsigned*)QV16;

        // pass 1: Q & K chains; attnqq; stage packed Q
        #pragma unroll 1
        for (int ct = 0; ct < 8; ++ct) {
            f32x4 aq = (f32x4)0.f, ak = (f32x4)0.f;
            #pragma unroll
            for (int ks = 0; ks < 4; ++ks) {
                const size_t bo = (size_t)((ks * 8 + ct) * 64 + lane) * 8;
                aq = __builtin_amdgcn_mfma_f32_16x16x32_bf16(afrag[ks], *(const bf16x8*)&Wqp[bo], aq, 0, 0, 0);
                ak = __builtin_amdgcn_mfma_f32_16x16x32_bf16(afrag[ks], *(const bf16x8*)&Wkp[bo], ak, 0, 0, 0);
            }
            const int col = ct * 16 + lr;
            const float bqv = bq[col], bkv = bk[col], av = avec[col];
            #pragma unroll
            for (int r = 0; r < 4; ++r) {
                const int row = lg * 4 + r;
                const float qv = aq[r] + bqv;
                const float kv = ak[r] + bkv;
                float part = av * prelu_f(qv + kv, al);
                part += swz_xor1(part);
                part += swz_xor2(part);
                part += swz_xor4(part);
                part += swz_xor8(part);
                const int grow = row0 + row;
                if (lr == 0 && grow < N) attnqq[(size_t)grow * NH + ct] = part;
                const float qn = swz_xor1(qv);
                if (evenlane) lds[wid][row][ct * 8 + (lr >> 1)] = cvt_pk_bf16(qv, qn);
            }
        }
        #pragma unroll
        for (int rr = 0; rr < 16; ++rr) {
            const int grow = row0 + rr;
            if (grow < N) qvout[(size_t)grow * 128 + lane] = lds[wid][rr][lane];
        }

        // pass 2: Vq chain; stage packed V
        #pragma unroll 1
        for (int ct = 0; ct < 8; ++ct) {
            f32x4 acv = (f32x4)0.f;
            #pragma unroll
            for (int ks = 0; ks < 4; ++ks) {
                const size_t bo = (size_t)((ks * 8 + ct) * 64 + lane) * 8;
                acv = __builtin_amdgcn_mfma_f32_16x16x32_bf16(afrag[ks], *(const bf16x8*)&Wvp[bo], acv, 0, 0, 0);
            }
            const int col = ct * 16 + lr;
            const float bvv = bv[col];
            #pragma unroll
            for (int r = 0; r < 4; ++r) {
                const int row = lg * 4 + r;
                const float vv = acv[r] + bvv;
                const float vn = swz_xor1(vv);
                if (evenlane) lds[wid][row][ct * 8 + (lr >> 1)] = cvt_pk_bf16(vv, vn);
            }
        }
        #pragma unroll
        for (int rr = 0; rr < 16; ++rr) {
            const int grow = row0 + rr;
            if (grow < N) qvout[(size_t)grow * 128 + 64 + lane] = lds[wid][rr][lane];
        }
    } else {
        const int row0 = (((int)blockIdx.x - nb) * 4 + wid) * 16;
        if (row0 >= M) return;
        const int arow = row0 + lr;
        const bool rowok = arow < M;
        unsigned* kvout = (unsigned*)KV16;

        // pass 1: K = key @ Wk
        {
            bf16x8 afK[4];
            #pragma unroll
            for (int ks = 0; ks < 4; ++ks) {
                float t[8] = {0.f,0.f,0.f,0.f,0.f,0.f,0.f,0.f};
                if (rowok) {
                    *(float4*)&t[0] = *(const float4*)&key[(size_t)arow * DIM + ks * 32 + lg * 8];
                    *(float4*)&t[4] = *(const float4*)&key[(size_t)arow * DIM + ks * 32 + lg * 8 + 4];
                }
                union { bf16x8 v; unsigned u[4]; } a;
                a.u[0] = cvt_pk_bf16(t[0], t[1]);
                a.u[1] = cvt_pk_bf16(t[2], t[3]);
                a.u[2] = cvt_pk_bf16(t[4], t[5]);
                a.u[3] = cvt_pk_bf16(t[6], t[7]);
                afK[ks] = a.v;
            }
            #pragma unroll 1
            for (int ct = 0; ct < 8; ++ct) {
                f32x4 ack = (f32x4)0.f;
                #pragma unroll
                for (int ks = 0; ks < 4; ++ks) {
                    const size_t bo = (size_t)((ks * 8 + ct) * 64 + lane) * 8;
                    ack = __builtin_amdgcn_mfma_f32_16x16x32_bf16(afK[ks], *(const bf16x8*)&Wkp[bo], ack, 0, 0, 0);
                }
                const int col = ct * 16 + lr;
                const float bkv = bk[col];
                #pragma unroll
                for (int r = 0; r < 4; ++r) {
                    const int row = lg * 4 + r;
                    const float kv = ack[r] + bkv;
                    const float kn = swz_xor1(kv);
                    if (evenlane) lds[wid][row][ct * 8 + (lr >> 1)] = cvt_pk_bf16(kv, kn);
                }
            }
            #pragma unroll
            for (int rr = 0; rr < 16; ++rr) {
                const int grow = row0 + rr;
                if (grow < M) kvout[(size_t)grow * 128 + lane] = lds[wid][rr][lane];
            }
        }
        // pass 2: V = value @ Wv
        {
            bf16x8 afV[4];
            #pragma unroll
            for (int ks = 0; ks < 4; ++ks) {
                float t[8] = {0.f,0.f,0.f,0.f,0.f,0.f,0.f,0.f};
                if (rowok) {
                    *(float4*)&t[0] = *(const float4*)&value[(size_t)arow * DIM + ks * 32 + lg * 8];
                    *(float4*)&t[4] = *(const float4*)&value[(size_t)arow * DIM + ks * 32 + lg * 8 + 4];
                }
                union { bf16x8 v; unsigned u[4]; } a;
                a.u[0] = cvt_pk_bf16(t[0], t[1]);
                a.u[1] = cvt_pk_bf16(t[2], t[3]);
                a.u[2] = cvt_pk_bf16(t[4], t[5]);
                a.u[3] = cvt_pk_bf16(t[6], t[7]);
                afV[ks] = a.v;
            }
            #pragma unroll 1
            for (int ct = 0; ct < 8; ++ct) {
                f32x4 acv = (f32x4)0.f;
                #pragma unroll
                for (int ks = 0; ks < 4; ++ks) {
                    const size_t bo = (size_t)((ks * 8 + ct) * 64 + lane) * 8;
                    acv = __builtin_amdgcn_mfma_f32_16x16x32_bf16(afV[ks], *(const bf16x8*)&Wvp[bo], acv, 0, 0, 0);
                }
                const int col = ct * 16 + lr;
                const float bvv = bv[col];
                #pragma unroll
                for (int r = 0; r < 4; ++r) {
                    const int row = lg * 4 + r;
                    const float vv = acv[r] + bvv;
                    const float vn = swz_xor1(vv);
                    if (evenlane) lds[wid][row][ct * 8 + (lr >> 1)] = cvt_pk_bf16(vv, vn);
                }
            }
            #pragma unroll
            for (int rr = 0; rr < 16; ++rr) {
                const int grow = row0 + rr;
                if (grow < M) kvout[(size_t)grow * 128 + 64 + lane] = lds[wid][rr][lane];
            }
        }
    }
}

// ------------------------------------------------------------------
// CSR scan chain
// ------------------------------------------------------------------
__global__ __launch_bounds__(256) void scan1_kernel(const int* __restrict__ counts,
                                                    int* __restrict__ bsum, int N)
{
    __shared__ int sh[256];
    int i = blockIdx.x * 256 + threadIdx.x;
    sh[threadIdx.x] = (i < N) ? counts[i] : 0;
    __syncthreads();
    #pragma unroll
    for (int off = 128; off; off >>= 1) {
        if (threadIdx.x < off) sh[threadIdx.x] += sh[threadIdx.x + off];
        __syncthreads();
    }
    if (threadIdx.x == 0) bsum[blockIdx.x] = sh[0];
}

__global__ __launch_bounds__(256) void scan2_kernel(const int* __restrict__ bsum,
                                                    int* __restrict__ boff, int B)
{
    int t = threadIdx.x;
    if (B > 256) {
        if (t == 0) { int run = 0; for (int i = 0; i < B; ++i) { int v = bsum[i]; boff[i] = run; run += v; } }
        return;
    }
    __shared__ int sh[256];
    int v = (t < B) ? bsum[t] : 0;
    sh[t] = v;
    __syncthreads();
    for (int off = 1; off < 256; off <<= 1) {
        int x = (t >= off) ? sh[t - off] : 0;
        __syncthreads();
        sh[t] += x;
        __syncthreads();
    }
    if (t < B) boff[t] = sh[t] - v;
}

__global__ __launch_bounds__(256) void scan3_kernel(const int* __restrict__ counts,
                                                    const int* __restrict__ boff,
                                                    int* __restrict__ offsets,
                                                    int* __restrict__ cursor,
                                                    int N, int E)
{
    __shared__ int sh[256];
    int t = threadIdx.x;
    int i = blockIdx.x * 256 + t;
    int v = (i < N) ? counts[i] : 0;
    sh[t] = v;
    __syncthreads();
    for (int off = 1; off < 256; off <<= 1) {
        int x = (t >= off) ? sh[t - off] : 0;
        __syncthreads();
        sh[t] += x;
        __syncthreads();
    }
    int base = boff[blockIdx.x];
    if (i < N) {
        int o = base + sh[t] - v;
        offsets[i] = o;
        cursor[i] = o;
    }
    if (i == 0) offsets[N] = E;
}

__global__ void fill_kernel(const int* __restrict__ qidx, const int* __restrict__ kidx,
                            int* __restrict__ cursor, int* __restrict__ ksorted, int E)
{
    for (int e = blockIdx.x * blockDim.x + threadIdx.x; e < E; e += gridDim.x * blockDim.x) {
        int q = qidx[e];
        int pos = atomicAdd(&cursor[q], 1);
        ksorted[pos] = kidx[e];
    }
}

// ------------------------------------------------------------------
// Edge aggregation v5: lane = (edge_slot e = lane>>3, head h = lane&7).
// In-lane scoring (16 dims), per-lane online-softmax partials with
// shared-m fast path, 3-round merge at the end.
// ------------------------------------------------------------------
__global__ __launch_bounds__(256) void edge_agg_kernel(
    const short* __restrict__ QV16, const float* __restrict__ attnqq,
    const short* __restrict__ KV16,
    const int* __restrict__ ksorted, const int* __restrict__ offsets,
    const float* __restrict__ avec, const float* __restrict__ alpha_p,
    short* __restrict__ msgn16, int N)
{
    const int wid = threadIdx.x >> 6;
    const int lane = threadIdx.x & 63;
    const int n = blockIdx.x * 4 + wid;
    if (n >= N) return;

    const int h = lane & 7;      // head
    const int e = lane >> 3;     // edge slot
    const float al = alpha_p[0];

    float c1[16], c2[16];
    {
        const float s1 = (1.f + al) * 0.5f, s2 = (1.f - al) * 0.5f;
        #pragma unroll
        for (int j = 0; j < 4; ++j) {
            const float4 a4 = *(const float4*)&avec[h * 16 + j * 4];
            c1[j*4+0] = a4.x * s1; c2[j*4+0] = a4.x * s2;
            c1[j*4+1] = a4.y * s1; c2[j*4+1] = a4.y * s2;
            c1[j*4+2] = a4.z * s1; c2[j*4+2] = a4.z * s2;
            c1[j*4+3] = a4.w * s1; c2[j*4+3] = a4.w * s2;
        }
    }

    const size_t qb = (size_t)n * 256 + h * 16;
    float q[16];
    {
        const uint4 lo = *(const uint4*)&QV16[qb];
        const uint4 hi = *(const uint4*)&QV16[qb + 8];
        const unsigned qd[8] = {lo.x, lo.y, lo.z, lo.w, hi.x, hi.y, hi.z, hi.w};
        #pragma unroll
        for (int j = 0; j < 8; ++j) { q[2*j] = bflo(qd[j]); q[2*j+1] = bfhi(qd[j]); }
    }

    float acc[16];
    float den;
    if (e == 0) {
        const uint4 lo = *(const uint4*)&QV16[qb + 128];
        const uint4 hi = *(const uint4*)&QV16[qb + 136];
        const unsigned vd[8] = {lo.x, lo.y, lo.z, lo.w, hi.x, hi.y, hi.z, hi.w};
        #pragma unroll
        for (int j = 0; j < 8; ++j) { acc[2*j] = bflo(vd[j]); acc[2*j+1] = bfhi(vd[j]); }
        den = 1.f;
    } else {
        #pragma unroll
        for (int d = 0; d < 16; ++d) acc[d] = 0.f;
        den = 0.f;
    }

    float m = attnqq[(size_t)n * NH + h];
    const int p0 = offsets[n], p1 = offsets[n + 1];
    bool div = false;

    int idx = p0 + e;
    bool valid = idx < p1;
    int ki = valid ? ksorted[idx] : 0;

    for (int base = p0; base < p1; base += 8) {
        const int cki = ki;
        const bool cval = valid;
        const int nidx = base + 8 + e;
        valid = nidx < p1;
        ki = valid ? ksorted[nidx] : 0;

        const size_t kb = (size_t)cki * 256 + h * 16;
        const uint4 klo = *(const uint4*)&KV16[kb];
        const uint4 khi = *(const uint4*)&KV16[kb + 8];
        const uint4 vlo = *(const uint4*)&KV16[kb + 128];
        const uint4 vhi = *(const uint4*)&KV16[kb + 136];
        const unsigned kd[8] = {klo.x, klo.y, klo.z, klo.w, khi.x, khi.y, khi.z, khi.w};
        const unsigned vd[8] = {vlo.x, vlo.y, vlo.z, vlo.w, vhi.x, vhi.y, vhi.z, vhi.w};

        float sA = 0.f, sB = 0.f;
        #pragma unroll
        for (int j = 0; j < 8; ++j) {
            const float x0 = q[2*j]   + bflo(kd[j]);
            const float x1 = q[2*j+1] + bfhi(kd[j]);
            sA = fmaf(c1[2*j],   x0, fmaf(c2[2*j],   __builtin_fabsf(x0), sA));
            sB = fmaf(c1[2*j+1], x1, fmaf(c2[2*j+1], __builtin_fabsf(x1), sB));
        }
        const float s = cval ? (sA + sB) : NEGINF;
        const float d_ = s - m;

        if (__any(d_ > 8.f)) {
            div = true;
            const float nm = fmaxf(m, s);
            const float c = __expf(m - nm);
            const float w = __expf(s - nm);
            den = den * c + w;
            #pragma unroll
            for (int j = 0; j < 8; ++j) {
                acc[2*j]   = fmaf(acc[2*j],   c, w * bflo(vd[j]));
                acc[2*j+1] = fmaf(acc[2*j+1], c, w * bfhi(vd[j]));
            }
            m = nm;
        } else {
            const float w = __expf(d_);
            den += w;
            #pragma unroll
            for (int j = 0; j < 8; ++j) {
                acc[2*j]   = fmaf(w, bflo(vd[j]), acc[2*j]);
                acc[2*j+1] = fmaf(w, bfhi(vd[j]), acc[2*j+1]);
            }
        }
    }

    #define MERGE_ROUND(SWZ)                                    \
        {                                                       \
            const float m2 = SWZ(m);                            \
            const float den2 = SWZ(den);                        \
            const float nm = fmaxf(m, m2);                      \
            const float ca = __expf(m - nm);                    \
            const float cb = __expf(m2 - nm);                   \
            den = den * ca + den2 * cb;                         \
            _Pragma("unroll")                                   \
            for (int d = 0; d < 16; ++d)                        \
                acc[d] = acc[d] * ca + SWZ(acc[d]) * cb;        \
            m = nm;                                             \
        }
    #define SUM_ROUND(SWZ)                                      \
        {                                                       \
            den += SWZ(den);                                    \
            _Pragma("unroll")                                   \
            for (int d = 0; d < 16; ++d) acc[d] += SWZ(acc[d]); \
        }

    if (div) {
        MERGE_ROUND(swz_xor8);
        MERGE_ROUND(swz_xor16);
        MERGE_ROUND(swz_xor32);
    } else {
        SUM_ROUND(swz_xor8);
        SUM_ROUND(swz_xor16);
        SUM_ROUND(swz_xor32);
    }
    #undef MERGE_ROUND
    #undef SUM_ROUND

    if (e == 0) {
        const float inv = 1.f / den;
        unsigned u[8];
        #pragma unroll
        for (int j = 0; j < 8; ++j)
            u[j] = cvt_pk_bf16(acc[2*j] * inv, acc[2*j+1] * inv);
        *(uint4*)&msgn16[(size_t)n * DIM + h * 16]     = make_uint4(u[0], u[1], u[2], u[3]);
        *(uint4*)&msgn16[(size_t)n * DIM + h * 16 + 8] = make_uint4(u[4], u[5], u[6], u[7]);
    }
}

// ------------------------------------------------------------------
// Output projection (MFMA, per-ct chains) + residual + LayerNorm.
// ------------------------------------------------------------------
__global__ __launch_bounds__(256) void out_ln_mfma(
    const short* __restrict__ msgn16, const short* __restrict__ Wpp,
    const float* __restrict__ bp, const float* __restrict__ query,
    const float* __restrict__ gamma, const float* __restrict__ beta,
    float* __restrict__ out, int N)
{
    __shared__ float ys[64][130];
    const int wid = threadIdx.x >> 6, lane = threadIdx.x & 63;
    const int rowbase = blockIdx.x * 64;
    const int row0 = rowbase + wid * 16;
    const int lr = lane & 15, lg = lane >> 4;

    if (row0 < N) {
        bf16x8 afrag[4];
        const int arow = row0 + lr;
        const bool rowok = arow < N;
        #pragma unroll
        for (int ks = 0; ks < 4; ++ks) {
            if (rowok)
                afrag[ks] = *(const bf16x8*)&msgn16[(size_t)arow * DIM + ks * 32 + lg * 8];
            else {
                bf16x8 z;
                #pragma unroll
                for (int j = 0; j < 8; ++j) z[j] = 0;
                afrag[ks] = z;
            }
        }
        #pragma unroll 1
        for (int ct = 0; ct < 8; ++ct) {
            f32x4 acc = (f32x4)0.f;
            #pragma unroll
            for (int ks = 0; ks < 4; ++ks) {
                const size_t bo = (size_t)((ks * 8 + ct) * 64 + lane) * 8;
                acc = __builtin_amdgcn_mfma_f32_16x16x32_bf16(afrag[ks], *(const bf16x8*)&Wpp[bo], acc, 0, 0, 0);
            }
            const int col = ct * 16 + lr;
            const float bpv = bp[col];
            #pragma unroll
            for (int r = 0; r < 4; ++r)
                ys[wid * 16 + lg * 4 + r][col] = acc[r] + bpv;
        }
    }
    __syncthreads();

    for (int rr = 0; rr < 16; ++rr) {
        const int r = wid * 16 + rr;
        const int grow = rowbase + r;
        if (grow >= N) break;
        const float y1 = ys[r][lane], y2 = ys[r][lane + 64];
        const float q1 = query[(size_t)grow * DIM + lane];
        const float q2 = query[(size_t)grow * DIM + lane + 64];
        const float r1 = y1 + q1, r2 = y2 + q2;
        float s = r1 + r2;
        float ss = r1 * r1 + r2 * r2;
        #pragma unroll
        for (int off = 32; off; off >>= 1) {
            s += __shfl_xor(s, off);
            ss += __shfl_xor(ss, off);
        }
        const float mu = s * (1.f / DIM);
        const float var = ss * (1.f / DIM) - mu * mu;
        const float rstd = rsqrtf(var + LN_EPS);
        out[(size_t)grow * DIM + lane] = gamma[lane] * (r1 - mu) * rstd + beta[lane];
        out[(size_t)grow * DIM + lane + 64] = gamma[lane + 64] * (r2 - mu) * rstd + beta[lane + 64];
    }
}

// ------------------------------------------------------------------
extern "C" void kernel_launch(void* const* d_in, const int* in_sizes, int n_in,
                              void* d_out, int out_size, void* d_ws, size_t ws_size,
                              hipStream_t stream) {
    const float* query = (const float*)d_in[0];
    const float* key   = (const float*)d_in[1];
    const float* value = (const float*)d_in[2];
    const int* query_idx = (const int*)d_in[3];
    const int* key_idx   = (const int*)d_in[4];
    const float* Wq = (const float*)d_in[5];
    const float* bq = (const float*)d_in[6];
    const float* Wk = (const float*)d_in[7];
    const float* bk = (const float*)d_in[8];
    const float* Wv = (const float*)d_in[9];
    const float* bv = (const float*)d_in[10];
    const float* Wp = (const float*)d_in[11];
    const float* bp = (const float*)d_in[12];
    const float* avec  = (const float*)d_in[13];
    const float* alpha = (const float*)d_in[14];
    const float* gamma = (const float*)d_in[15];
    const float* beta  = (const float*)d_in[16];
    float* out = (float*)d_out;

    const int N = in_sizes[0] / DIM;
    const int M = in_sizes[1] / DIM;
    const int E = in_sizes[3];

    // workspace layout (16B aligned)
    float* f = (float*)d_ws;
    float* attnqq = f;  f += (size_t)N * NH;
    short* sp = (short*)f;
    short* QV16 = sp;   sp += (size_t)N * 256;
    short* KV16 = sp;   sp += (size_t)M * 256;
    short* msgn16 = sp; sp += (size_t)N * DIM;
    short* Wqp = sp;    sp += DIM * DIM;
    short* Wkp = sp;    sp += DIM * DIM;
    short* Wvp = sp;    sp += DIM * DIM;
    short* Wpp = sp;    sp += DIM * DIM;
    int* ip = (int*)(((size_t)sp + 15) & ~(size_t)15);
    int* counts  = ip;  ip += N;
    int* offsets = ip;  ip += N + 1;
    int* cursor  = ip;  ip += N;
    int* bsum    = ip;  ip += 4096;
    int* boff    = ip;  ip += 4096;
    int* ksorted = ip;  ip += E;

    const int B = (N + 255) / 256;
    const int nb = (N + 63) / 64;
    const int mb = (M + 63) / 64;

    hipMemsetAsync(counts, 0, (size_t)N * sizeof(int), stream);

    setup_kernel<<<1056, 256, 0, stream>>>(Wq, Wk, Wv, Wp, Wqp, Wkp, Wvp, Wpp,
                                           query_idx, counts, E);

    scan1_kernel<<<B, 256, 0, stream>>>(counts, bsum, N);
    scan2_kernel<<<1, 256, 0, stream>>>(bsum, boff, B);
    scan3_kernel<<<B, 256, 0, stream>>>(counts, boff, offsets, cursor, N, E);
    fill_kernel<<<1024, 256, 0, stream>>>(query_idx, key_idx, cursor, ksorted, E);

    proj_all_mfma<<<nb + mb, 256, 0, stream>>>(
        query, key, value, Wqp, Wkp, Wvp, bq, bk, bv, avec, alpha,
        QV16, attnqq, KV16, N, M, nb);

    edge_agg_kernel<<<(N + 3) / 4, 256, 0, stream>>>(
        QV16, attnqq, KV16, ksorted, offsets, avec, alpha, msgn16, N);

    out_ln_mfma<<<(N + 63) / 64, 256, 0, stream>>>(
        msgn16, Wpp, bp, query, gamma, beta, out, N);
}